// Round 10
// baseline (1265.459 us; speedup 1.0000x reference)
//
#include <hip/hip_runtime.h>
#include <math.h>

#define NN 50000
#define NE 500000
#define EEDG 550000          // NE + NN self loops
#define SDIM 128             // STRUCT
#define MDIM 768             // SEM
#define HIDD 128             // HID
#define NHEADS 4
#define INDIM 896            // STRUCT + SEM
#define H1D 512              // HEADS*HID
#define SCAN_NB 196          // ceil(NN/256)
#define MP 50048             // NN padded to 128*391
#define MT 391               // row tiles of 128
#define EB 2149              // ceil(EEDG/256)
#define NPART 32             // stat partial buffers

typedef unsigned short u16;
typedef unsigned int u32;
typedef __attribute__((ext_vector_type(8))) short short8;
typedef __attribute__((ext_vector_type(4))) float f32x4;

// ---------------- bf16 helpers ----------------
__device__ __forceinline__ u16 f2bf(float f) {
    union { float f; u32 u; } v; v.f = f;
    u32 r = v.u + 0x7FFFu + ((v.u >> 16) & 1u);
    return (u16)(r >> 16);
}
__device__ __forceinline__ float bf2f(u16 h) {
    union { u32 u; float f; } v; v.u = ((u32)h) << 16;
    return v.f;
}

__device__ __forceinline__ void gl_lds16(const u16* g, u16* l) {
    __builtin_amdgcn_global_load_lds(
        (const __attribute__((address_space(1))) void*)g,
        (__attribute__((address_space(3))) void*)l, 16, 0, 0);
}

// ---------------- utility ----------------
__device__ __forceinline__ void edge_sd(const int* __restrict__ ei, int e, int& s, int& d) {
    if (e < NE) { s = ei[e]; d = ei[NE + e]; }
    else        { s = e - NE; d = e - NE; }
}

// ---------------- fused init: weight casts (transposed) + zero fills ----------------
// zero region: degcur/cur (2*NN ints) + [msum|vsum|statm|statv] (33792 floats)
__global__ __launch_bounds__(256) void cast_weights(
    const float* __restrict__ Wq, const float* __restrict__ Wk, const float* __restrict__ Wv,
    const float* __restrict__ Wo, const float* __restrict__ W1, const float* __restrict__ W2,
    u16* __restrict__ wqT, u16* __restrict__ wkT, u16* __restrict__ wvT,
    u16* __restrict__ woT, u16* __restrict__ w1T, u16* __restrict__ w2T,
    int* __restrict__ degcur, float* __restrict__ msum)
{
    const int SQ = 128 * 128, SK = 128 * 768, SV = 128 * 768,
              SO = 256 * 128, S1 = 896 * 512, S2 = 512 * 128;
    long i = (long)blockIdx.x * 256 + threadIdx.x;
    long w = i;
    if (w < SQ) { int n = (int)(w / 128), k = (int)(w % 128); wqT[w] = f2bf(Wq[(size_t)k * 128 + n]); return; }
    w -= SQ;
    if (w < SK) { int n = (int)(w / 768), k = (int)(w % 768); wkT[w] = f2bf(Wk[(size_t)k * 128 + n]); return; }
    w -= SK;
    if (w < SV) { int n = (int)(w / 768), k = (int)(w % 768); wvT[w] = f2bf(Wv[(size_t)k * 128 + n]); return; }
    w -= SV;
    if (w < SO) { int n = (int)(w / 256), k = (int)(w % 256); woT[w] = f2bf(Wo[(size_t)k * 128 + n]); return; }
    w -= SO;
    if (w < S1) { int n = (int)(w / 896), k = (int)(w % 896); w1T[w] = f2bf(W1[(size_t)k * 512 + n]); return; }
    w -= S1;
    if (w < S2) { int n = (int)(w / 512), k = (int)(w % 512); w2T[w] = f2bf(W2[(size_t)k * 128 + n]); return; }
    w -= S2;
    if (w < 2 * NN) { degcur[w] = 0; return; }
    w -= 2 * NN;
    if (w < 1024 + 2 * NPART * 512) msum[w] = 0.f;
}

// ---------------- fused: count_deg + x cast/pad ----------------
__global__ __launch_bounds__(256) void prep2(const int* __restrict__ ei, int* __restrict__ deg,
                                             const float4* __restrict__ x4, u16* __restrict__ xb)
{
    if (blockIdx.x < EB) {
        int e = blockIdx.x * 256 + threadIdx.x;
        if (e >= EEDG) return;
        int d = e < NE ? ei[NE + e] : e - NE;
        atomicAdd(&deg[d], 1);
        return;
    }
    const long total = (long)MP * 224;
    long i = (long)(blockIdx.x - EB) * 256 + threadIdx.x;
    long stride = (long)(gridDim.x - EB) * 256;
    for (; i < total; i += stride) {
        int row = (int)(i / 224);
        int c4 = (int)(i - (long)row * 224);
        float4 v = make_float4(0.f, 0.f, 0.f, 0.f);
        if (row < NN) v = x4[(size_t)row * 224 + c4];
        short4 o;
        o.x = (short)f2bf(v.x); o.y = (short)f2bf(v.y);
        o.z = (short)f2bf(v.z); o.w = (short)f2bf(v.w);
        *(short4*)(xb + (size_t)row * 896 + c4 * 4) = o;
    }
}

// ---------------- CSR scan ----------------
__global__ __launch_bounds__(256) void scan_bsum(const int* __restrict__ deg, int* __restrict__ part) {
    __shared__ int s[256];
    int t = threadIdx.x;
    int idx = blockIdx.x * 256 + t;
    s[t] = idx < NN ? deg[idx] : 0;
    __syncthreads();
    for (int off = 128; off; off >>= 1) {
        if (t < off) s[t] += s[t + off];
        __syncthreads();
    }
    if (t == 0) part[blockIdx.x] = s[0];
}

__global__ __launch_bounds__(256) void scan_part(int* __restrict__ part) {
    __shared__ int s[256];
    int t = threadIdx.x;
    int v = t < SCAN_NB ? part[t] : 0;
    s[t] = v;
    __syncthreads();
    for (int off = 1; off < 256; off <<= 1) {
        int x = t >= off ? s[t - off] : 0;
        __syncthreads();
        s[t] += x;
        __syncthreads();
    }
    if (t < SCAN_NB) part[t] = s[t] - v;   // exclusive
}

__global__ __launch_bounds__(256) void scan_write(const int* __restrict__ deg, const int* __restrict__ part,
                                                  int* __restrict__ rowptr) {
    __shared__ int s[256];
    int t = threadIdx.x;
    int idx = blockIdx.x * 256 + t;
    int v = idx < NN ? deg[idx] : 0;
    s[t] = v;
    __syncthreads();
    for (int off = 1; off < 256; off <<= 1) {
        int x = t >= off ? s[t - off] : 0;
        __syncthreads();
        s[t] += x;
        __syncthreads();
    }
    if (idx < NN) rowptr[idx] = part[blockIdx.x] + s[t] - v;
    if (idx == NN - 1) rowptr[NN] = EEDG;
}

// ---------------- CSR-ordered per-edge softmax numerators ----------------
template<int H>
__global__ __launch_bounds__(256) void edge_exp(const int* __restrict__ esrc, const int* __restrict__ edst,
    const float* __restrict__ asrc, const float* __restrict__ adst, float* __restrict__ exf)
{
    int i = blockIdx.x * 256 + threadIdx.x;
    if (i >= EEDG) return;
    int s = esrc[i], d = edst[i];
    if (H == 4) {
        float4 as = *(const float4*)(asrc + s * 4);
        float4 ad = *(const float4*)(adst + d * 4);
        float4 o;
        float a;
        a = as.x + ad.x; a = a >= 0.f ? a : 0.2f * a; o.x = expf(a);
        a = as.y + ad.y; a = a >= 0.f ? a : 0.2f * a; o.y = expf(a);
        a = as.z + ad.z; a = a >= 0.f ? a : 0.2f * a; o.z = expf(a);
        a = as.w + ad.w; a = a >= 0.f ? a : 0.2f * a; o.w = expf(a);
        *(float4*)(exf + (size_t)i * 4) = o;
    } else {
        float a = asrc[s] + adst[d];
        a = a >= 0.f ? a : 0.2f * a;
        exf[i] = expf(a);
    }
}

// ---------------- MFMA bf16 GEMM body (optional fused att-dot epilogue) ----------------
template<int OUT_BF16, int DOTS, int DH>
__device__ __forceinline__ void gemm_body(
    u16* __restrict__ Asm, u16* __restrict__ Bsm,
    const u16* __restrict__ A1, int lda1, int K1,
    const u16* __restrict__ A2, int lda2, int K2,
    const u16* __restrict__ Bw,
    void* __restrict__ Cout, int ldc,
    const float* __restrict__ bias, int row0, int col0,
    const float* __restrict__ dvs, const float* __restrict__ dvd,
    float* __restrict__ aout_s, float* __restrict__ aout_d)
{
    const int tid = threadIdx.x;
    const int wave = tid >> 6, lane = tid & 63;
    const int wr = wave >> 1, wc = wave & 1;
    const int K = K1 + K2;
    const int srow = tid >> 2;
    const int skp = (tid & 3) * 8;
    const int l15 = lane & 15, l4 = lane >> 4;

    f32x4 acc[4][4];
    #pragma unroll
    for (int i = 0; i < 4; ++i)
        #pragma unroll
        for (int j = 0; j < 4; ++j)
            acc[i][j] = (f32x4){0.f, 0.f, 0.f, 0.f};

    for (int k0 = 0; k0 < K; k0 += 32) {
        const u16* Ab; int la; int kk;
        if (k0 < K1) { Ab = A1; la = lda1; kk = k0; }
        else         { Ab = A2; la = lda2; kk = k0 - K1; }
        gl_lds16(Ab + (size_t)(row0 + srow) * la + kk + skp,      Asm + srow * 32 + skp);
        gl_lds16(Ab + (size_t)(row0 + srow + 64) * la + kk + skp, Asm + (srow + 64) * 32 + skp);
        gl_lds16(Bw + (size_t)(col0 + srow) * K + k0 + skp,       Bsm + srow * 32 + skp);
        gl_lds16(Bw + (size_t)(col0 + srow + 64) * K + k0 + skp,  Bsm + (srow + 64) * 32 + skp);
        __syncthreads();
        short8 af[4], bfr[4];
        #pragma unroll
        for (int m = 0; m < 4; ++m)
            af[m] = *(const short8*)(Asm + (wr * 64 + m * 16 + l15) * 32 + l4 * 8);
        #pragma unroll
        for (int n = 0; n < 4; ++n)
            bfr[n] = *(const short8*)(Bsm + (wc * 64 + n * 16 + l15) * 32 + l4 * 8);
        #pragma unroll
        for (int m = 0; m < 4; ++m)
            #pragma unroll
            for (int n = 0; n < 4; ++n)
                acc[m][n] = __builtin_amdgcn_mfma_f32_16x16x32_bf16(af[m], bfr[n], acc[m][n], 0, 0, 0);
        __syncthreads();
    }
    #pragma unroll
    for (int m = 0; m < 4; ++m) {
        int r = row0 + wr * 64 + m * 16 + l4 * 4;
        #pragma unroll
        for (int n = 0; n < 4; ++n) {
            int c = col0 + wc * 64 + n * 16 + l15;
            float bv = bias ? bias[c] : 0.f;
            #pragma unroll
            for (int q = 0; q < 4; ++q) {
                float v = acc[m][n][q] + bv;
                if (OUT_BF16) ((u16*)Cout)[(size_t)(r + q) * ldc + c] = f2bf(v);
                else          ((float*)Cout)[(size_t)(r + q) * ldc + c] = v;
            }
        }
    }
    if (DOTS) {
        const int head = (DH == 1) ? 0 : (col0 >> 7);
        const float* svp = dvs + head * 128;
        const float* dvp = dvd + head * 128;
        float sv[4], dv[4];
        #pragma unroll
        for (int n = 0; n < 4; ++n) {
            int cc = wc * 64 + n * 16 + l15;
            sv[n] = svp[cc];
            dv[n] = dvp[cc];
        }
        __shared__ float red[128][2][2];
        #pragma unroll
        for (int m = 0; m < 4; ++m) {
            #pragma unroll
            for (int q = 0; q < 4; ++q) {
                float ps = 0.f, pd = 0.f;
                #pragma unroll
                for (int n = 0; n < 4; ++n) {
                    ps = fmaf(acc[m][n][q], sv[n], ps);
                    pd = fmaf(acc[m][n][q], dv[n], pd);
                }
                #pragma unroll
                for (int off = 1; off < 16; off <<= 1) {
                    ps += __shfl_xor(ps, off);
                    pd += __shfl_xor(pd, off);
                }
                if (l15 == 0) {
                    int lr = wr * 64 + m * 16 + l4 * 4 + q;
                    red[lr][wc][0] = ps;
                    red[lr][wc][1] = pd;
                }
            }
        }
        __syncthreads();
        if (tid < 128) {
            int r = row0 + tid;
            aout_s[(size_t)r * DH + head] = red[tid][0][0] + red[tid][1][0];
            aout_d[(size_t)r * DH + head] = red[tid][0][1] + red[tid][1][1];
        }
    }
}

template<int OUT_BF16, int DOTS, int DH>
__global__ __launch_bounds__(256) void gemm_mfma(
    const u16* __restrict__ A1, int lda1, int K1,
    const u16* __restrict__ A2, int lda2, int K2,
    const u16* __restrict__ Bw,
    void* __restrict__ Cout, int ldc,
    const float* __restrict__ bias,
    const float* __restrict__ dvs, const float* __restrict__ dvd,
    float* __restrict__ aout_s, float* __restrict__ aout_d)
{
    __shared__ u16 Asm[128 * 32];
    __shared__ u16 Bsm[128 * 32];
    gemm_body<OUT_BF16, DOTS, DH>(Asm, Bsm, A1, lda1, K1, A2, lda2, K2, Bw, Cout, ldc, bias,
                                  blockIdx.y * 128, blockIdx.x * 128, dvs, dvd, aout_s, aout_d);
}

// W1 GEMM: 1D grid, bijective XCD-chunked swizzle, col-tile fastest per XCD span.
__global__ __launch_bounds__(256) void gemm_w1(
    const u16* __restrict__ A1, const u16* __restrict__ A2,
    const u16* __restrict__ Bw, u16* __restrict__ Cout)
{
    __shared__ u16 Asm[128 * 32];
    __shared__ u16 Bsm[128 * 32];
    const int nwg = 4 * MT;            // 1564
    const int q = nwg / 8, r = nwg % 8;
    int orig = blockIdx.x;
    int xcd = orig & 7;
    int lg = (xcd < r ? xcd * (q + 1) : r * (q + 1) + (xcd - r) * q) + (orig >> 3);
    int col0 = (lg & 3) * 128;
    int row0 = (lg >> 2) * 128;
    gemm_body<1, 0, 1>(Asm, Bsm, A1, 128, 128, A2, 896, 768, Bw, Cout, 512, nullptr,
                       row0, col0, nullptr, nullptr, nullptr, nullptr);
}

// fused Q|K|V GEMM + fill_csr (independent work overlapped in one dispatch)
__global__ __launch_bounds__(256) void gemm_qkv_fill(
    const u16* __restrict__ xb,
    const u16* __restrict__ wqT, const u16* __restrict__ wkT, const u16* __restrict__ wvT,
    u16* __restrict__ qb, u16* __restrict__ kb, u16* __restrict__ vb,
    const int* __restrict__ ei, const int* __restrict__ rowptr,
    int* __restrict__ cur, int* __restrict__ esrc, int* __restrict__ edst)
{
    __shared__ u16 Asm[128 * 32];
    __shared__ u16 Bsm[128 * 32];
    int bid = blockIdx.x;
    if (bid >= 3 * MT) {
        int e = (bid - 3 * MT) * 256 + threadIdx.x;
        if (e >= EEDG) return;
        int s, d;
        edge_sd(ei, e, s, d);
        int p = rowptr[d] + atomicAdd(&cur[d], 1);
        esrc[p] = s;
        edst[p] = d;
        return;
    }
    int sel = bid / MT;
    int row = bid - sel * MT;
    const u16* A; const u16* B; int K; u16* C;
    if (sel == 0)      { A = xb;       B = wqT; K = 128; C = qb; }
    else if (sel == 1) { A = xb + 128; B = wkT; K = 768; C = kb; }
    else               { A = xb + 128; B = wvT; K = 768; C = vb; }
    gemm_body<1, 0, 1>(Asm, Bsm, A, 896, K, (const u16*)nullptr, 0, 0, B, C, 128, nullptr,
                       row * 128, 0, nullptr, nullptr, nullptr, nullptr);
}

// ---------------- node cross-attention (bf16): V *= sigmoid(dot(Q,K)) ----------------
__global__ __launch_bounds__(128) void node_attn_b(const u16* __restrict__ Q,
                                                   const u16* __restrict__ K,
                                                   u16* __restrict__ V)
{
    int nd = blockIdx.x;
    int t = threadIdx.x;
    size_t base = (size_t)nd * HIDD;
    float p = bf2f(Q[base + t]) * bf2f(K[base + t]);
    #pragma unroll
    for (int off = 32; off; off >>= 1) p += __shfl_down(p, off);
    __shared__ float sm[2];
    if ((t & 63) == 0) sm[t >> 6] = p;
    __syncthreads();
    float s = sm[0] + sm[1];
    float sig = 1.f / (1.f + expf(-s));
    V[base + t] = f2bf(bf2f(V[base + t]) * sig);
}

// ---------------- GAT layer-1 attention dots (from h1) ----------------
__global__ __launch_bounds__(256) void att_dots1_b(const u16* __restrict__ h1,
    const float* __restrict__ asv, const float* __restrict__ adv,
    float* __restrict__ a_src, float* __restrict__ a_dst)
{
    int nd = blockIdx.x;
    int t = threadIdx.x;
    int w = t >> 6, l = t & 63;
    const u16* hr = h1 + (size_t)nd * H1D + w * HIDD;
    const float* sv = asv + w * HIDD;
    const float* dv = adv + w * HIDD;
    float h0v = bf2f(hr[l]), h1v = bf2f(hr[l + 64]);
    float ps = h0v * sv[l] + h1v * sv[l + 64];
    float pd = h0v * dv[l] + h1v * dv[l + 64];
    #pragma unroll
    for (int off = 32; off; off >>= 1) {
        ps += __shfl_down(ps, off);
        pd += __shfl_down(pd, off);
    }
    if (l == 0) { a_src[nd * NHEADS + w] = ps; a_dst[nd * NHEADS + w] = pd; }
}

// ---------------- fused softmax + gather aggregation + norm1 stats ----------------
// 128 threads x 4 cols (uint2), 8-edge unroll; epilogue accumulates column
// sums/sumsq (rounded values, matching old colstat_b) into 32-way partials.
#define ACC4(P, AA) { \
    n0 = fmaf(bf2f((u16)(P).x), AA, n0); \
    n1 = fmaf(bf2f((u16)((P).x >> 16)), AA, n1); \
    n2 = fmaf(bf2f((u16)(P).y), AA, n2); \
    n3 = fmaf(bf2f((u16)((P).y >> 16)), AA, n3); }

__global__ __launch_bounds__(128) void agg1_f(const int* __restrict__ rowptr, const int* __restrict__ esrc,
    const float* __restrict__ exf,
    const u16* __restrict__ h1b, const float* __restrict__ bias, u16* __restrict__ o1b,
    float* __restrict__ statm, float* __restrict__ statv)
{
    int d = blockIdx.x;
    int t = threadIdx.x;
    int c0 = t * 4;
    int h = t >> 5;
    int beg = rowptr[d], end = rowptr[d + 1];
    float n0 = 0.f, n1 = 0.f, n2 = 0.f, n3 = 0.f, den = 0.f;
    int i = beg;
    for (; i + 7 < end; i += 8) {
        int s0 = esrc[i], s1 = esrc[i+1], s2 = esrc[i+2], s3 = esrc[i+3];
        int s4 = esrc[i+4], s5 = esrc[i+5], s6 = esrc[i+6], s7 = esrc[i+7];
        float a0 = exf[(size_t)i*4+h],     a1 = exf[(size_t)(i+1)*4+h];
        float a2 = exf[(size_t)(i+2)*4+h], a3 = exf[(size_t)(i+3)*4+h];
        float a4 = exf[(size_t)(i+4)*4+h], a5 = exf[(size_t)(i+5)*4+h];
        float a6 = exf[(size_t)(i+6)*4+h], a7 = exf[(size_t)(i+7)*4+h];
        uint2 p0 = *(const uint2*)(h1b + (size_t)s0 * H1D + c0);
        uint2 p1 = *(const uint2*)(h1b + (size_t)s1 * H1D + c0);
        uint2 p2 = *(const uint2*)(h1b + (size_t)s2 * H1D + c0);
        uint2 p3 = *(const uint2*)(h1b + (size_t)s3 * H1D + c0);
        uint2 p4 = *(const uint2*)(h1b + (size_t)s4 * H1D + c0);
        uint2 p5 = *(const uint2*)(h1b + (size_t)s5 * H1D + c0);
        uint2 p6 = *(const uint2*)(h1b + (size_t)s6 * H1D + c0);
        uint2 p7 = *(const uint2*)(h1b + (size_t)s7 * H1D + c0);
        den += ((a0 + a1) + (a2 + a3)) + ((a4 + a5) + (a6 + a7));
        ACC4(p0, a0) ACC4(p1, a1) ACC4(p2, a2) ACC4(p3, a3)
        ACC4(p4, a4) ACC4(p5, a5) ACC4(p6, a6) ACC4(p7, a7)
    }
    for (; i < end; ++i) {
        int sA = esrc[i];
        float aA = exf[(size_t)i * 4 + h];
        uint2 pA = *(const uint2*)(h1b + (size_t)sA * H1D + c0);
        den += aA;
        ACC4(pA, aA)
    }
    float invd = 1.f / (den + 1e-16f);
    float4 bv = *(const float4*)(bias + c0);
    u16 q0 = f2bf(n0 * invd + bv.x);
    u16 q1 = f2bf(n1 * invd + bv.y);
    u16 q2 = f2bf(n2 * invd + bv.z);
    u16 q3 = f2bf(n3 * invd + bv.w);
    *(uint2*)(o1b + (size_t)d * H1D + c0) =
        make_uint2((u32)q0 | ((u32)q1 << 16), (u32)q2 | ((u32)q3 << 16));
    // norm1 stats on rounded values (identical to old colstat_b pass)
    float r0 = bf2f(q0), r1 = bf2f(q1), r2 = bf2f(q2), r3 = bf2f(q3);
    float* sm_ = statm + (d & (NPART - 1)) * 512 + c0;
    float* sv_ = statv + (d & (NPART - 1)) * 512 + c0;
    atomicAdd(sm_ + 0, r0); atomicAdd(sv_ + 0, r0 * r0);
    atomicAdd(sm_ + 1, r1); atomicAdd(sv_ + 1, r1 * r1);
    atomicAdd(sm_ + 2, r2); atomicAdd(sv_ + 2, r2 * r2);
    atomicAdd(sm_ + 3, r3); atomicAdd(sv_ + 3, r3 * r3);
}

// layer 2: wave per dst (4/block); block 0 zeroes msum/vsum for norm2.
__global__ __launch_bounds__(256) void agg2_f(const int* __restrict__ rowptr, const int* __restrict__ esrc,
    const float* __restrict__ exf,
    const u16* __restrict__ h2b, const float* __restrict__ bias, float* __restrict__ o2,
    float* __restrict__ msum)
{
    if (blockIdx.x == 0) {
        msum[threadIdx.x] = 0.f;
        msum[threadIdx.x + 256] = 0.f;
        msum[threadIdx.x + 512] = 0.f;
        msum[threadIdx.x + 768] = 0.f;
    }
    int w = threadIdx.x >> 6, l = threadIdx.x & 63;
    int d = blockIdx.x * 4 + w;
    if (d >= NN) return;
    int c0 = l * 2;
    int beg = rowptr[d], end = rowptr[d + 1];
    float n0 = 0.f, n1 = 0.f, den = 0.f;
    int i = beg;
    for (; i + 7 < end; i += 8) {
        int s0 = esrc[i], s1 = esrc[i+1], s2 = esrc[i+2], s3 = esrc[i+3];
        int s4 = esrc[i+4], s5 = esrc[i+5], s6 = esrc[i+6], s7 = esrc[i+7];
        float a0 = exf[i],   a1 = exf[i+1], a2 = exf[i+2], a3 = exf[i+3];
        float a4 = exf[i+4], a5 = exf[i+5], a6 = exf[i+6], a7 = exf[i+7];
        u32 p0 = *(const u32*)(h2b + (size_t)s0 * HIDD + c0);
        u32 p1 = *(const u32*)(h2b + (size_t)s1 * HIDD + c0);
        u32 p2 = *(const u32*)(h2b + (size_t)s2 * HIDD + c0);
        u32 p3 = *(const u32*)(h2b + (size_t)s3 * HIDD + c0);
        u32 p4 = *(const u32*)(h2b + (size_t)s4 * HIDD + c0);
        u32 p5 = *(const u32*)(h2b + (size_t)s5 * HIDD + c0);
        u32 p6 = *(const u32*)(h2b + (size_t)s6 * HIDD + c0);
        u32 p7 = *(const u32*)(h2b + (size_t)s7 * HIDD + c0);
        den += ((a0 + a1) + (a2 + a3)) + ((a4 + a5) + (a6 + a7));
        n0 = fmaf(bf2f((u16)p0), a0, n0); n1 = fmaf(bf2f((u16)(p0 >> 16)), a0, n1);
        n0 = fmaf(bf2f((u16)p1), a1, n0); n1 = fmaf(bf2f((u16)(p1 >> 16)), a1, n1);
        n0 = fmaf(bf2f((u16)p2), a2, n0); n1 = fmaf(bf2f((u16)(p2 >> 16)), a2, n1);
        n0 = fmaf(bf2f((u16)p3), a3, n0); n1 = fmaf(bf2f((u16)(p3 >> 16)), a3, n1);
        n0 = fmaf(bf2f((u16)p4), a4, n0); n1 = fmaf(bf2f((u16)(p4 >> 16)), a4, n1);
        n0 = fmaf(bf2f((u16)p5), a5, n0); n1 = fmaf(bf2f((u16)(p5 >> 16)), a5, n1);
        n0 = fmaf(bf2f((u16)p6), a6, n0); n1 = fmaf(bf2f((u16)(p6 >> 16)), a6, n1);
        n0 = fmaf(bf2f((u16)p7), a7, n0); n1 = fmaf(bf2f((u16)(p7 >> 16)), a7, n1);
    }
    for (; i < end; ++i) {
        int sA = esrc[i];
        float aA = exf[i];
        u32 pA = *(const u32*)(h2b + (size_t)sA * HIDD + c0);
        den += aA;
        n0 = fmaf(bf2f((u16)pA), aA, n0);
        n1 = fmaf(bf2f((u16)(pA >> 16)), aA, n1);
    }
    float invd = 1.f / (den + 1e-16f);
    o2[(size_t)d * HIDD + c0]     = n0 * invd + bias[c0];
    o2[(size_t)d * HIDD + c0 + 1] = n1 * invd + bias[c0 + 1];
}

// ---------------- norm1 apply (reads 32-way partial stats) + ELU ----------------
__global__ void apply_norm_elu_b(u16* __restrict__ x, const float* __restrict__ statm,
                                 const float* __restrict__ statv, const float* __restrict__ ms,
                                 const float* __restrict__ w, const float* __restrict__ b,
                                 int n, int rpb)
{
    int C = blockDim.x;
    int c = threadIdx.x;
    float msum_ = 0.f, vsum_ = 0.f;
    #pragma unroll
    for (int p = 0; p < NPART; ++p) {
        msum_ += statm[p * 512 + c];
        vsum_ += statv[p * 512 + c];
    }
    const float invn = 1.f / (float)NN;
    float mean = msum_ * invn;
    float sub = mean * ms[c];
    float var = vsum_ * invn - 2.f * sub * mean + sub * sub;
    float inv = rsqrtf(var + 1e-5f);
    float wc = w[c] * inv, bc = b[c];
    int r0 = blockIdx.x * rpb;
    int r1 = min(n, r0 + rpb);
    for (int r = r0; r < r1; ++r) {
        float v = (bf2f(x[(size_t)r * C + c]) - sub) * wc + bc;
        v = v > 0.f ? v : expm1f(v);
        x[(size_t)r * C + c] = f2bf(v);
    }
}

// ---------------- layer-2 column stats (f32) ----------------
__global__ void colstat(const float* __restrict__ x, float* __restrict__ msum,
                        float* __restrict__ vsum, int n, int rpb)
{
    int C = blockDim.x;
    int c = threadIdx.x;
    int r0 = blockIdx.x * rpb;
    int r1 = min(n, r0 + rpb);
    float s = 0.f, s2 = 0.f;
    for (int r = r0; r < r1; ++r) {
        float v = x[(size_t)r * C + c];
        s += v;
        s2 += v * v;
    }
    atomicAdd(&msum[c], s);
    atomicAdd(&vsum[c], s2);
}

// ---------------- fused norm2 + ELU + final projection ----------------
__global__ __launch_bounds__(128) void norm2_proj(const float* __restrict__ o2,
    const float* __restrict__ msum, const float* __restrict__ vsum,
    const float* __restrict__ ms, const float* __restrict__ w, const float* __restrict__ b,
    const float* __restrict__ Wn, const float* __restrict__ bn, float* __restrict__ out)
{
    int nd = blockIdx.x;
    int t = threadIdx.x;
    const float invn = 1.f / (float)NN;
    float mean = msum[t] * invn;
    float sub = mean * ms[t];
    float var = vsum[t] * invn - 2.f * sub * mean + sub * sub;
    float inv = rsqrtf(var + 1e-5f);
    float v = (o2[(size_t)nd * HIDD + t] - sub) * w[t] * inv + b[t];
    v = v > 0.f ? v : expm1f(v);
    float p0 = v * Wn[t * 2], p1 = v * Wn[t * 2 + 1];
    #pragma unroll
    for (int off = 32; off; off >>= 1) {
        p0 += __shfl_down(p0, off);
        p1 += __shfl_down(p1, off);
    }
    __shared__ float sm[4];
    if ((t & 63) == 0) { sm[t >> 6] = p0; sm[2 + (t >> 6)] = p1; }
    __syncthreads();
    if (t == 0) {
        out[nd * 2 + 0] = sm[0] + sm[1] + bn[0];
        out[nd * 2 + 1] = sm[2] + sm[3] + bn[1];
    }
}

// ---------------- host launch ----------------
extern "C" void kernel_launch(void* const* d_in, const int* in_sizes, int n_in,
                              void* d_out, int out_size, void* d_ws, size_t ws_size,
                              hipStream_t stream)
{
    const float* x   = (const float*)d_in[0];
    const int*   ei  = (const int*)d_in[1];
    const float* Wq  = (const float*)d_in[2];
    const float* Wk  = (const float*)d_in[3];
    const float* Wv  = (const float*)d_in[4];
    const float* Wo  = (const float*)d_in[5];
    const float* bo  = (const float*)d_in[6];
    const float* W1  = (const float*)d_in[7];
    const float* as1 = (const float*)d_in[8];
    const float* ad1 = (const float*)d_in[9];
    const float* b1  = (const float*)d_in[10];
    const float* g1w = (const float*)d_in[11];
    const float* g1b = (const float*)d_in[12];
    const float* g1m = (const float*)d_in[13];
    const float* W2  = (const float*)d_in[14];
    const float* as2 = (const float*)d_in[15];
    const float* ad2 = (const float*)d_in[16];
    const float* b2  = (const float*)d_in[17];
    const float* g2w = (const float*)d_in[18];
    const float* g2b = (const float*)d_in[19];
    const float* g2m = (const float*)d_in[20];
    const float* Wn  = (const float*)d_in[21];
    const float* bn  = (const float*)d_in[22];
    float* out = (float*)d_out;

    // ---- workspace layout ----
    u16* usw = (u16*)d_ws;
    size_t uo = 0;
    u16* xb  = usw + uo; uo += (size_t)MP * 896;
    u16* h1b = usw + uo; uo += (size_t)MP * 512;
    u16* qb  = usw + uo; uo += (size_t)MP * 128;
    u16* kb  = usw + uo; uo += (size_t)MP * 128;   // later h2b
    u16* vb  = usw + uo; uo += (size_t)MP * 128;
    u16* o1b = usw + uo; uo += (size_t)MP * 512;
    u16* wqT = usw + uo; uo += 128 * 128;
    u16* wkT = usw + uo; uo += 128 * 768;
    u16* wvT = usw + uo; uo += 128 * 768;
    u16* woT = usw + uo; uo += 128 * 256;
    u16* w1T = usw + uo; uo += 512 * 896;
    u16* w2T = usw + uo; uo += 128 * 512;
    float* fws = (float*)(usw + uo);
    size_t fo = 0;
    float* asrc = fws + fo; fo += (size_t)MP * NHEADS;
    float* adst = fws + fo; fo += (size_t)MP * NHEADS;
    float* exf  = fws + fo; fo += (size_t)EEDG * NHEADS;
    float* msum = fws + fo; fo += 512;
    float* vsum = fws + fo; fo += 512;
    float* statm = fws + fo; fo += NPART * 512;
    float* statv = fws + fo; fo += NPART * 512;
    int* iws = (int*)(fws + fo);
    size_t io = 0;
    int* rowptr = iws + io; io += NN + 1;
    int* degcur = iws + io; io += 2 * NN;     // [deg | cur]
    int* esrc   = iws + io; io += EEDG;
    int* edst   = iws + io; io += EEDG;
    int* spart  = iws + io; io += 256;
    int* cur    = degcur + NN;
    float* o2  = (float*)xb;   // xb free after h1 GEMM
    u16* h0b = qb;             // reuse q after node_attn
    u16* h2b = kb;             // reuse k after node_attn

    // cast_weights linear work: 770048 weights + 100000 ints + (1024 + 32768) floats
    const int CW_BLOCKS = (770048 + 2 * NN + 1024 + 2 * NPART * 512 + 255) / 256;

    // --- init: weight casts + all zero fills ---
    cast_weights<<<CW_BLOCKS, 256, 0, stream>>>(Wq, Wk, Wv, Wo, W1, W2,
                                                wqT, wkT, wvT, woT, w1T, w2T,
                                                degcur, msum);
    // --- count_deg + x cast (fused, independent work) ---
    prep2<<<EB + 8192, 256, 0, stream>>>(ei, degcur, (const float4*)x, xb);

    // --- CSR scan ---
    scan_bsum<<<SCAN_NB, 256, 0, stream>>>(degcur, spart);
    scan_part<<<1, 256, 0, stream>>>(spart);
    scan_write<<<SCAN_NB, 256, 0, stream>>>(degcur, spart, rowptr);

    // --- Q|K|V GEMM + fill_csr overlapped in one dispatch ---
    gemm_qkv_fill<<<3 * MT + EB, 256, 0, stream>>>(xb, wqT, wkT, wvT, qb, kb, vb,
                                                   ei, rowptr, cur, esrc, edst);
    node_attn_b<<<NN, 128, 0, stream>>>(qb, kb, vb);

    // --- h0 = [x_struct | attn] @ Wo + bo ---
    gemm_mfma<1, 0, 1><<<dim3(1, MT), 256, 0, stream>>>(xb, 896, 128, vb, 128, 128, woT, h0b, 128, bo,
                                                        nullptr, nullptr, nullptr, nullptr);

    // --- h1 = [h0 | x_sem] @ W1 (XCD-swizzled 1D grid) ---
    gemm_w1<<<4 * MT, 256, 0, stream>>>(h0b, xb + 128, w1T, h1b);

    // --- GAT layer 1: dots -> CSR-ordered edge exp -> gather + fused stats ---
    att_dots1_b<<<NN, 256, 0, stream>>>(h1b, as1, ad1, asrc, adst);
    edge_exp<NHEADS><<<EB, 256, 0, stream>>>(esrc, edst, asrc, adst, exf);
    agg1_f<<<NN, 128, 0, stream>>>(rowptr, esrc, exf, h1b, b1, o1b, statm, statv);

    // --- graph norm 1 apply + ELU (stats from partials) ---
    apply_norm_elu_b<<<(NN + 127) / 128, H1D, 0, stream>>>(o1b, statm, statv, g1m, g1w, g1b, NN, 128);

    // --- GAT layer 2: W2 GEMM with fused att-dots ---
    gemm_mfma<1, 1, 1><<<dim3(1, MT), 256, 0, stream>>>(o1b, 512, 512, (const u16*)nullptr, 0, 0, w2T, h2b, 128,
                                                        nullptr, as2, ad2, asrc, adst);
    edge_exp<1><<<EB, 256, 0, stream>>>(esrc, edst, asrc, adst, exf);
    agg2_f<<<(NN + 3) / 4, 256, 0, stream>>>(rowptr, esrc, exf, h2b, b2, o2, msum);

    // --- graph norm 2 + ELU + projection ---
    colstat<<<(NN + 127) / 128, HIDD, 0, stream>>>(o2, msum, vsum, NN, 128);
    norm2_proj<<<NN, 128, 0, stream>>>(o2, msum, vsum, g2m, g2w, g2b, Wn, bn, out);
}

// Round 11
// 590.682 us; speedup vs baseline: 2.1424x; 2.1424x over previous
//
#include <hip/hip_runtime.h>
#include <math.h>

#define NN 50000
#define NE 500000
#define EEDG 550000          // NE + NN self loops
#define SDIM 128             // STRUCT
#define MDIM 768             // SEM
#define HIDD 128             // HID
#define NHEADS 4
#define INDIM 896            // STRUCT + SEM
#define H1D 512              // HEADS*HID
#define SCAN_NB 196          // ceil(NN/256)
#define MP 50048             // NN padded to 128*391
#define MT 391               // row tiles of 128
#define EB 2149              // ceil(EEDG/256)

typedef unsigned short u16;
typedef unsigned int u32;
typedef __attribute__((ext_vector_type(8))) short short8;
typedef __attribute__((ext_vector_type(4))) float f32x4;

// ---------------- bf16 helpers ----------------
__device__ __forceinline__ u16 f2bf(float f) {
    union { float f; u32 u; } v; v.f = f;
    u32 r = v.u + 0x7FFFu + ((v.u >> 16) & 1u);
    return (u16)(r >> 16);
}
__device__ __forceinline__ float bf2f(u16 h) {
    union { u32 u; float f; } v; v.u = ((u32)h) << 16;
    return v.f;
}

__device__ __forceinline__ void gl_lds16(const u16* g, u16* l) {
    __builtin_amdgcn_global_load_lds(
        (const __attribute__((address_space(1))) void*)g,
        (__attribute__((address_space(3))) void*)l, 16, 0, 0);
}

// ---------------- utility ----------------
__device__ __forceinline__ void edge_sd(const int* __restrict__ ei, int e, int& s, int& d) {
    if (e < NE) { s = ei[e]; d = ei[NE + e]; }
    else        { s = e - NE; d = e - NE; }
}

// ---------------- fused init: weight casts (transposed) + zero fills ----------------
__global__ __launch_bounds__(256) void cast_weights(
    const float* __restrict__ Wq, const float* __restrict__ Wk, const float* __restrict__ Wv,
    const float* __restrict__ Wo, const float* __restrict__ W1, const float* __restrict__ W2,
    u16* __restrict__ wqT, u16* __restrict__ wkT, u16* __restrict__ wvT,
    u16* __restrict__ woT, u16* __restrict__ w1T, u16* __restrict__ w2T,
    int* __restrict__ degcur, float* __restrict__ msum)
{
    const int SQ = 128 * 128, SK = 128 * 768, SV = 128 * 768,
              SO = 256 * 128, S1 = 896 * 512, S2 = 512 * 128;
    long i = (long)blockIdx.x * 256 + threadIdx.x;
    long w = i;
    if (w < SQ) { int n = (int)(w / 128), k = (int)(w % 128); wqT[w] = f2bf(Wq[(size_t)k * 128 + n]); return; }
    w -= SQ;
    if (w < SK) { int n = (int)(w / 768), k = (int)(w % 768); wkT[w] = f2bf(Wk[(size_t)k * 128 + n]); return; }
    w -= SK;
    if (w < SV) { int n = (int)(w / 768), k = (int)(w % 768); wvT[w] = f2bf(Wv[(size_t)k * 128 + n]); return; }
    w -= SV;
    if (w < SO) { int n = (int)(w / 256), k = (int)(w % 256); woT[w] = f2bf(Wo[(size_t)k * 128 + n]); return; }
    w -= SO;
    if (w < S1) { int n = (int)(w / 896), k = (int)(w % 896); w1T[w] = f2bf(W1[(size_t)k * 512 + n]); return; }
    w -= S1;
    if (w < S2) { int n = (int)(w / 512), k = (int)(w % 512); w2T[w] = f2bf(W2[(size_t)k * 128 + n]); return; }
    w -= S2;
    if (w < 2 * NN) { degcur[w] = 0; return; }
    w -= 2 * NN;
    if (w < 1024) msum[w] = 0.f;
}

// ---------------- fused: count_deg + x cast/pad ----------------
__global__ __launch_bounds__(256) void prep2(const int* __restrict__ ei, int* __restrict__ deg,
                                             const float4* __restrict__ x4, u16* __restrict__ xb)
{
    if (blockIdx.x < EB) {
        int e = blockIdx.x * 256 + threadIdx.x;
        if (e >= EEDG) return;
        int d = e < NE ? ei[NE + e] : e - NE;
        atomicAdd(&deg[d], 1);
        return;
    }
    const long total = (long)MP * 224;
    long i = (long)(blockIdx.x - EB) * 256 + threadIdx.x;
    long stride = (long)(gridDim.x - EB) * 256;
    for (; i < total; i += stride) {
        int row = (int)(i / 224);
        int c4 = (int)(i - (long)row * 224);
        float4 v = make_float4(0.f, 0.f, 0.f, 0.f);
        if (row < NN) v = x4[(size_t)row * 224 + c4];
        short4 o;
        o.x = (short)f2bf(v.x); o.y = (short)f2bf(v.y);
        o.z = (short)f2bf(v.z); o.w = (short)f2bf(v.w);
        *(short4*)(xb + (size_t)row * 896 + c4 * 4) = o;
    }
}

// ---------------- CSR scan ----------------
__global__ __launch_bounds__(256) void scan_bsum(const int* __restrict__ deg, int* __restrict__ part) {
    __shared__ int s[256];
    int t = threadIdx.x;
    int idx = blockIdx.x * 256 + t;
    s[t] = idx < NN ? deg[idx] : 0;
    __syncthreads();
    for (int off = 128; off; off >>= 1) {
        if (t < off) s[t] += s[t + off];
        __syncthreads();
    }
    if (t == 0) part[blockIdx.x] = s[0];
}

__global__ __launch_bounds__(256) void scan_part(int* __restrict__ part) {
    __shared__ int s[256];
    int t = threadIdx.x;
    int v = t < SCAN_NB ? part[t] : 0;
    s[t] = v;
    __syncthreads();
    for (int off = 1; off < 256; off <<= 1) {
        int x = t >= off ? s[t - off] : 0;
        __syncthreads();
        s[t] += x;
        __syncthreads();
    }
    if (t < SCAN_NB) part[t] = s[t] - v;   // exclusive
}

__global__ __launch_bounds__(256) void scan_write(const int* __restrict__ deg, const int* __restrict__ part,
                                                  int* __restrict__ rowptr) {
    __shared__ int s[256];
    int t = threadIdx.x;
    int idx = blockIdx.x * 256 + t;
    int v = idx < NN ? deg[idx] : 0;
    s[t] = v;
    __syncthreads();
    for (int off = 1; off < 256; off <<= 1) {
        int x = t >= off ? s[t - off] : 0;
        __syncthreads();
        s[t] += x;
        __syncthreads();
    }
    if (idx < NN) rowptr[idx] = part[blockIdx.x] + s[t] - v;
    if (idx == NN - 1) rowptr[NN] = EEDG;
}

// ---------------- CSR-ordered per-edge softmax numerators ----------------
template<int H>
__global__ __launch_bounds__(256) void edge_exp(const int* __restrict__ esrc, const int* __restrict__ edst,
    const float* __restrict__ asrc, const float* __restrict__ adst, float* __restrict__ exf)
{
    int i = blockIdx.x * 256 + threadIdx.x;
    if (i >= EEDG) return;
    int s = esrc[i], d = edst[i];
    if (H == 4) {
        float4 as = *(const float4*)(asrc + s * 4);
        float4 ad = *(const float4*)(adst + d * 4);
        float4 o;
        float a;
        a = as.x + ad.x; a = a >= 0.f ? a : 0.2f * a; o.x = expf(a);
        a = as.y + ad.y; a = a >= 0.f ? a : 0.2f * a; o.y = expf(a);
        a = as.z + ad.z; a = a >= 0.f ? a : 0.2f * a; o.z = expf(a);
        a = as.w + ad.w; a = a >= 0.f ? a : 0.2f * a; o.w = expf(a);
        *(float4*)(exf + (size_t)i * 4) = o;
    } else {
        float a = asrc[s] + adst[d];
        a = a >= 0.f ? a : 0.2f * a;
        exf[i] = expf(a);
    }
}

// ---------------- MFMA bf16 GEMM body (optional fused att-dot epilogue) ----------------
template<int OUT_BF16, int DOTS, int DH>
__device__ __forceinline__ void gemm_body(
    u16* __restrict__ Asm, u16* __restrict__ Bsm,
    const u16* __restrict__ A1, int lda1, int K1,
    const u16* __restrict__ A2, int lda2, int K2,
    const u16* __restrict__ Bw,
    void* __restrict__ Cout, int ldc,
    const float* __restrict__ bias, int row0, int col0,
    const float* __restrict__ dvs, const float* __restrict__ dvd,
    float* __restrict__ aout_s, float* __restrict__ aout_d)
{
    const int tid = threadIdx.x;
    const int wave = tid >> 6, lane = tid & 63;
    const int wr = wave >> 1, wc = wave & 1;
    const int K = K1 + K2;
    const int srow = tid >> 2;
    const int skp = (tid & 3) * 8;
    const int l15 = lane & 15, l4 = lane >> 4;

    f32x4 acc[4][4];
    #pragma unroll
    for (int i = 0; i < 4; ++i)
        #pragma unroll
        for (int j = 0; j < 4; ++j)
            acc[i][j] = (f32x4){0.f, 0.f, 0.f, 0.f};

    for (int k0 = 0; k0 < K; k0 += 32) {
        const u16* Ab; int la; int kk;
        if (k0 < K1) { Ab = A1; la = lda1; kk = k0; }
        else         { Ab = A2; la = lda2; kk = k0 - K1; }
        gl_lds16(Ab + (size_t)(row0 + srow) * la + kk + skp,      Asm + srow * 32 + skp);
        gl_lds16(Ab + (size_t)(row0 + srow + 64) * la + kk + skp, Asm + (srow + 64) * 32 + skp);
        gl_lds16(Bw + (size_t)(col0 + srow) * K + k0 + skp,       Bsm + srow * 32 + skp);
        gl_lds16(Bw + (size_t)(col0 + srow + 64) * K + k0 + skp,  Bsm + (srow + 64) * 32 + skp);
        __syncthreads();
        short8 af[4], bfr[4];
        #pragma unroll
        for (int m = 0; m < 4; ++m)
            af[m] = *(const short8*)(Asm + (wr * 64 + m * 16 + l15) * 32 + l4 * 8);
        #pragma unroll
        for (int n = 0; n < 4; ++n)
            bfr[n] = *(const short8*)(Bsm + (wc * 64 + n * 16 + l15) * 32 + l4 * 8);
        #pragma unroll
        for (int m = 0; m < 4; ++m)
            #pragma unroll
            for (int n = 0; n < 4; ++n)
                acc[m][n] = __builtin_amdgcn_mfma_f32_16x16x32_bf16(af[m], bfr[n], acc[m][n], 0, 0, 0);
        __syncthreads();
    }
    #pragma unroll
    for (int m = 0; m < 4; ++m) {
        int r = row0 + wr * 64 + m * 16 + l4 * 4;
        #pragma unroll
        for (int n = 0; n < 4; ++n) {
            int c = col0 + wc * 64 + n * 16 + l15;
            float bv = bias ? bias[c] : 0.f;
            #pragma unroll
            for (int q = 0; q < 4; ++q) {
                float v = acc[m][n][q] + bv;
                if (OUT_BF16) ((u16*)Cout)[(size_t)(r + q) * ldc + c] = f2bf(v);
                else          ((float*)Cout)[(size_t)(r + q) * ldc + c] = v;
            }
        }
    }
    if (DOTS) {
        const int head = (DH == 1) ? 0 : (col0 >> 7);
        const float* svp = dvs + head * 128;
        const float* dvp = dvd + head * 128;
        float sv[4], dv[4];
        #pragma unroll
        for (int n = 0; n < 4; ++n) {
            int cc = wc * 64 + n * 16 + l15;
            sv[n] = svp[cc];
            dv[n] = dvp[cc];
        }
        __shared__ float red[128][2][2];
        #pragma unroll
        for (int m = 0; m < 4; ++m) {
            #pragma unroll
            for (int q = 0; q < 4; ++q) {
                float ps = 0.f, pd = 0.f;
                #pragma unroll
                for (int n = 0; n < 4; ++n) {
                    ps = fmaf(acc[m][n][q], sv[n], ps);
                    pd = fmaf(acc[m][n][q], dv[n], pd);
                }
                #pragma unroll
                for (int off = 1; off < 16; off <<= 1) {
                    ps += __shfl_xor(ps, off);
                    pd += __shfl_xor(pd, off);
                }
                if (l15 == 0) {
                    int lr = wr * 64 + m * 16 + l4 * 4 + q;
                    red[lr][wc][0] = ps;
                    red[lr][wc][1] = pd;
                }
            }
        }
        __syncthreads();
        if (tid < 128) {
            int r = row0 + tid;
            aout_s[(size_t)r * DH + head] = red[tid][0][0] + red[tid][1][0];
            aout_d[(size_t)r * DH + head] = red[tid][0][1] + red[tid][1][1];
        }
    }
}

template<int OUT_BF16, int DOTS, int DH>
__global__ __launch_bounds__(256) void gemm_mfma(
    const u16* __restrict__ A1, int lda1, int K1,
    const u16* __restrict__ A2, int lda2, int K2,
    const u16* __restrict__ Bw,
    void* __restrict__ Cout, int ldc,
    const float* __restrict__ bias,
    const float* __restrict__ dvs, const float* __restrict__ dvd,
    float* __restrict__ aout_s, float* __restrict__ aout_d)
{
    __shared__ u16 Asm[128 * 32];
    __shared__ u16 Bsm[128 * 32];
    gemm_body<OUT_BF16, DOTS, DH>(Asm, Bsm, A1, lda1, K1, A2, lda2, K2, Bw, Cout, ldc, bias,
                                  blockIdx.y * 128, blockIdx.x * 128, dvs, dvd, aout_s, aout_d);
}

// W1 GEMM: 1D grid, bijective XCD-chunked swizzle, col-tile fastest per XCD span.
__global__ __launch_bounds__(256) void gemm_w1(
    const u16* __restrict__ A1, const u16* __restrict__ A2,
    const u16* __restrict__ Bw, u16* __restrict__ Cout)
{
    __shared__ u16 Asm[128 * 32];
    __shared__ u16 Bsm[128 * 32];
    const int nwg = 4 * MT;            // 1564
    const int q = nwg / 8, r = nwg % 8;
    int orig = blockIdx.x;
    int xcd = orig & 7;
    int lg = (xcd < r ? xcd * (q + 1) : r * (q + 1) + (xcd - r) * q) + (orig >> 3);
    int col0 = (lg & 3) * 128;
    int row0 = (lg >> 2) * 128;
    gemm_body<1, 0, 1>(Asm, Bsm, A1, 128, 128, A2, 896, 768, Bw, Cout, 512, nullptr,
                       row0, col0, nullptr, nullptr, nullptr, nullptr);
}

// fused Q|K|V GEMM + fill_csr (independent work overlapped in one dispatch)
__global__ __launch_bounds__(256) void gemm_qkv_fill(
    const u16* __restrict__ xb,
    const u16* __restrict__ wqT, const u16* __restrict__ wkT, const u16* __restrict__ wvT,
    u16* __restrict__ qb, u16* __restrict__ kb, u16* __restrict__ vb,
    const int* __restrict__ ei, const int* __restrict__ rowptr,
    int* __restrict__ cur, int* __restrict__ esrc, int* __restrict__ edst)
{
    __shared__ u16 Asm[128 * 32];
    __shared__ u16 Bsm[128 * 32];
    int bid = blockIdx.x;
    if (bid >= 3 * MT) {
        int e = (bid - 3 * MT) * 256 + threadIdx.x;
        if (e >= EEDG) return;
        int s, d;
        edge_sd(ei, e, s, d);
        int p = rowptr[d] + atomicAdd(&cur[d], 1);
        esrc[p] = s;
        edst[p] = d;
        return;
    }
    int sel = bid / MT;
    int row = bid - sel * MT;
    const u16* A; const u16* B; int K; u16* C;
    if (sel == 0)      { A = xb;       B = wqT; K = 128; C = qb; }
    else if (sel == 1) { A = xb + 128; B = wkT; K = 768; C = kb; }
    else               { A = xb + 128; B = wvT; K = 768; C = vb; }
    gemm_body<1, 0, 1>(Asm, Bsm, A, 896, K, (const u16*)nullptr, 0, 0, B, C, 128, nullptr,
                       row * 128, 0, nullptr, nullptr, nullptr, nullptr);
}

// ---------------- node cross-attention (bf16): V *= sigmoid(dot(Q,K)) ----------------
__global__ __launch_bounds__(128) void node_attn_b(const u16* __restrict__ Q,
                                                   const u16* __restrict__ K,
                                                   u16* __restrict__ V)
{
    int nd = blockIdx.x;
    int t = threadIdx.x;
    size_t base = (size_t)nd * HIDD;
    float p = bf2f(Q[base + t]) * bf2f(K[base + t]);
    #pragma unroll
    for (int off = 32; off; off >>= 1) p += __shfl_down(p, off);
    __shared__ float sm[2];
    if ((t & 63) == 0) sm[t >> 6] = p;
    __syncthreads();
    float s = sm[0] + sm[1];
    float sig = 1.f / (1.f + expf(-s));
    V[base + t] = f2bf(bf2f(V[base + t]) * sig);
}

// ---------------- GAT layer-1 attention dots (from h1) ----------------
__global__ __launch_bounds__(256) void att_dots1_b(const u16* __restrict__ h1,
    const float* __restrict__ asv, const float* __restrict__ adv,
    float* __restrict__ a_src, float* __restrict__ a_dst)
{
    int nd = blockIdx.x;
    int t = threadIdx.x;
    int w = t >> 6, l = t & 63;
    const u16* hr = h1 + (size_t)nd * H1D + w * HIDD;
    const float* sv = asv + w * HIDD;
    const float* dv = adv + w * HIDD;
    float h0v = bf2f(hr[l]), h1v = bf2f(hr[l + 64]);
    float ps = h0v * sv[l] + h1v * sv[l + 64];
    float pd = h0v * dv[l] + h1v * dv[l + 64];
    #pragma unroll
    for (int off = 32; off; off >>= 1) {
        ps += __shfl_down(ps, off);
        pd += __shfl_down(pd, off);
    }
    if (l == 0) { a_src[nd * NHEADS + w] = ps; a_dst[nd * NHEADS + w] = pd; }
}

// ---------------- fused softmax + gather aggregation (barrier-free, 8-deep MLP) ----------------
// 128 threads x 4 cols (uint2), 8-edge unroll.
#define ACC4(P, AA) { \
    n0 = fmaf(bf2f((u16)(P).x), AA, n0); \
    n1 = fmaf(bf2f((u16)((P).x >> 16)), AA, n1); \
    n2 = fmaf(bf2f((u16)(P).y), AA, n2); \
    n3 = fmaf(bf2f((u16)((P).y >> 16)), AA, n3); }

__global__ __launch_bounds__(128) void agg1_f(const int* __restrict__ rowptr, const int* __restrict__ esrc,
    const float* __restrict__ exf,
    const u16* __restrict__ h1b, const float* __restrict__ bias, u16* __restrict__ o1b)
{
    int d = blockIdx.x;
    int t = threadIdx.x;
    int c0 = t * 4;
    int h = t >> 5;
    int beg = rowptr[d], end = rowptr[d + 1];
    float n0 = 0.f, n1 = 0.f, n2 = 0.f, n3 = 0.f, den = 0.f;
    int i = beg;
    for (; i + 7 < end; i += 8) {
        int s0 = esrc[i], s1 = esrc[i+1], s2 = esrc[i+2], s3 = esrc[i+3];
        int s4 = esrc[i+4], s5 = esrc[i+5], s6 = esrc[i+6], s7 = esrc[i+7];
        float a0 = exf[(size_t)i*4+h],     a1 = exf[(size_t)(i+1)*4+h];
        float a2 = exf[(size_t)(i+2)*4+h], a3 = exf[(size_t)(i+3)*4+h];
        float a4 = exf[(size_t)(i+4)*4+h], a5 = exf[(size_t)(i+5)*4+h];
        float a6 = exf[(size_t)(i+6)*4+h], a7 = exf[(size_t)(i+7)*4+h];
        uint2 p0 = *(const uint2*)(h1b + (size_t)s0 * H1D + c0);
        uint2 p1 = *(const uint2*)(h1b + (size_t)s1 * H1D + c0);
        uint2 p2 = *(const uint2*)(h1b + (size_t)s2 * H1D + c0);
        uint2 p3 = *(const uint2*)(h1b + (size_t)s3 * H1D + c0);
        uint2 p4 = *(const uint2*)(h1b + (size_t)s4 * H1D + c0);
        uint2 p5 = *(const uint2*)(h1b + (size_t)s5 * H1D + c0);
        uint2 p6 = *(const uint2*)(h1b + (size_t)s6 * H1D + c0);
        uint2 p7 = *(const uint2*)(h1b + (size_t)s7 * H1D + c0);
        den += ((a0 + a1) + (a2 + a3)) + ((a4 + a5) + (a6 + a7));
        ACC4(p0, a0) ACC4(p1, a1) ACC4(p2, a2) ACC4(p3, a3)
        ACC4(p4, a4) ACC4(p5, a5) ACC4(p6, a6) ACC4(p7, a7)
    }
    for (; i < end; ++i) {
        int sA = esrc[i];
        float aA = exf[(size_t)i * 4 + h];
        uint2 pA = *(const uint2*)(h1b + (size_t)sA * H1D + c0);
        den += aA;
        ACC4(pA, aA)
    }
    float invd = 1.f / (den + 1e-16f);
    float4 bv = *(const float4*)(bias + c0);
    u32 o0 = (u32)f2bf(n0 * invd + bv.x) | ((u32)f2bf(n1 * invd + bv.y) << 16);
    u32 o1 = (u32)f2bf(n2 * invd + bv.z) | ((u32)f2bf(n3 * invd + bv.w) << 16);
    *(uint2*)(o1b + (size_t)d * H1D + c0) = make_uint2(o0, o1);
}

// layer 2: wave per dst (4/block); block 0 zeroes msum/vsum for norm2.
__global__ __launch_bounds__(256) void agg2_f(const int* __restrict__ rowptr, const int* __restrict__ esrc,
    const float* __restrict__ exf,
    const u16* __restrict__ h2b, const float* __restrict__ bias, float* __restrict__ o2,
    float* __restrict__ msum)
{
    if (blockIdx.x == 0) {
        msum[threadIdx.x] = 0.f;
        msum[threadIdx.x + 256] = 0.f;
        msum[threadIdx.x + 512] = 0.f;
        msum[threadIdx.x + 768] = 0.f;
    }
    int w = threadIdx.x >> 6, l = threadIdx.x & 63;
    int d = blockIdx.x * 4 + w;
    if (d >= NN) return;
    int c0 = l * 2;
    int beg = rowptr[d], end = rowptr[d + 1];
    float n0 = 0.f, n1 = 0.f, den = 0.f;
    int i = beg;
    for (; i + 7 < end; i += 8) {
        int s0 = esrc[i], s1 = esrc[i+1], s2 = esrc[i+2], s3 = esrc[i+3];
        int s4 = esrc[i+4], s5 = esrc[i+5], s6 = esrc[i+6], s7 = esrc[i+7];
        float a0 = exf[i],   a1 = exf[i+1], a2 = exf[i+2], a3 = exf[i+3];
        float a4 = exf[i+4], a5 = exf[i+5], a6 = exf[i+6], a7 = exf[i+7];
        u32 p0 = *(const u32*)(h2b + (size_t)s0 * HIDD + c0);
        u32 p1 = *(const u32*)(h2b + (size_t)s1 * HIDD + c0);
        u32 p2 = *(const u32*)(h2b + (size_t)s2 * HIDD + c0);
        u32 p3 = *(const u32*)(h2b + (size_t)s3 * HIDD + c0);
        u32 p4 = *(const u32*)(h2b + (size_t)s4 * HIDD + c0);
        u32 p5 = *(const u32*)(h2b + (size_t)s5 * HIDD + c0);
        u32 p6 = *(const u32*)(h2b + (size_t)s6 * HIDD + c0);
        u32 p7 = *(const u32*)(h2b + (size_t)s7 * HIDD + c0);
        den += ((a0 + a1) + (a2 + a3)) + ((a4 + a5) + (a6 + a7));
        n0 = fmaf(bf2f((u16)p0), a0, n0); n1 = fmaf(bf2f((u16)(p0 >> 16)), a0, n1);
        n0 = fmaf(bf2f((u16)p1), a1, n0); n1 = fmaf(bf2f((u16)(p1 >> 16)), a1, n1);
        n0 = fmaf(bf2f((u16)p2), a2, n0); n1 = fmaf(bf2f((u16)(p2 >> 16)), a2, n1);
        n0 = fmaf(bf2f((u16)p3), a3, n0); n1 = fmaf(bf2f((u16)(p3 >> 16)), a3, n1);
        n0 = fmaf(bf2f((u16)p4), a4, n0); n1 = fmaf(bf2f((u16)(p4 >> 16)), a4, n1);
        n0 = fmaf(bf2f((u16)p5), a5, n0); n1 = fmaf(bf2f((u16)(p5 >> 16)), a5, n1);
        n0 = fmaf(bf2f((u16)p6), a6, n0); n1 = fmaf(bf2f((u16)(p6 >> 16)), a6, n1);
        n0 = fmaf(bf2f((u16)p7), a7, n0); n1 = fmaf(bf2f((u16)(p7 >> 16)), a7, n1);
    }
    for (; i < end; ++i) {
        int sA = esrc[i];
        float aA = exf[i];
        u32 pA = *(const u32*)(h2b + (size_t)sA * HIDD + c0);
        den += aA;
        n0 = fmaf(bf2f((u16)pA), aA, n0);
        n1 = fmaf(bf2f((u16)(pA >> 16)), aA, n1);
    }
    float invd = 1.f / (den + 1e-16f);
    o2[(size_t)d * HIDD + c0]     = n0 * invd + bias[c0];
    o2[(size_t)d * HIDD + c0 + 1] = n1 * invd + bias[c0 + 1];
}

// ---------------- graph norm ----------------
__global__ void colstat_b(const u16* __restrict__ x, float* __restrict__ msum,
                          float* __restrict__ vsum, int n, int rpb)
{
    int C = blockDim.x;
    int c = threadIdx.x;
    int r0 = blockIdx.x * rpb;
    int r1 = min(n, r0 + rpb);
    float s = 0.f, s2 = 0.f;
    for (int r = r0; r < r1; ++r) {
        float v = bf2f(x[(size_t)r * C + c]);
        s += v;
        s2 += v * v;
    }
    atomicAdd(&msum[c], s);
    atomicAdd(&vsum[c], s2);
}

__global__ void apply_norm_elu_b(u16* __restrict__ x, const float* __restrict__ msum,
                                 const float* __restrict__ vsum, const float* __restrict__ ms,
                                 const float* __restrict__ w, const float* __restrict__ b,
                                 int n, int rpb)
{
    int C = blockDim.x;
    int c = threadIdx.x;
    const float invn = 1.f / (float)NN;
    float mean = msum[c] * invn;
    float sub = mean * ms[c];
    float var = vsum[c] * invn - 2.f * sub * mean + sub * sub;
    float inv = rsqrtf(var + 1e-5f);
    float wc = w[c] * inv, bc = b[c];
    int r0 = blockIdx.x * rpb;
    int r1 = min(n, r0 + rpb);
    for (int r = r0; r < r1; ++r) {
        float v = (bf2f(x[(size_t)r * C + c]) - sub) * wc + bc;
        v = v > 0.f ? v : expm1f(v);
        x[(size_t)r * C + c] = f2bf(v);
    }
}

__global__ void colstat(const float* __restrict__ x, float* __restrict__ msum,
                        float* __restrict__ vsum, int n, int rpb)
{
    int C = blockDim.x;
    int c = threadIdx.x;
    int r0 = blockIdx.x * rpb;
    int r1 = min(n, r0 + rpb);
    float s = 0.f, s2 = 0.f;
    for (int r = r0; r < r1; ++r) {
        float v = x[(size_t)r * C + c];
        s += v;
        s2 += v * v;
    }
    atomicAdd(&msum[c], s);
    atomicAdd(&vsum[c], s2);
}

// ---------------- fused norm2 + ELU + final projection ----------------
__global__ __launch_bounds__(128) void norm2_proj(const float* __restrict__ o2,
    const float* __restrict__ msum, const float* __restrict__ vsum,
    const float* __restrict__ ms, const float* __restrict__ w, const float* __restrict__ b,
    const float* __restrict__ Wn, const float* __restrict__ bn, float* __restrict__ out)
{
    int nd = blockIdx.x;
    int t = threadIdx.x;
    const float invn = 1.f / (float)NN;
    float mean = msum[t] * invn;
    float sub = mean * ms[t];
    float var = vsum[t] * invn - 2.f * sub * mean + sub * sub;
    float inv = rsqrtf(var + 1e-5f);
    float v = (o2[(size_t)nd * HIDD + t] - sub) * w[t] * inv + b[t];
    v = v > 0.f ? v : expm1f(v);
    float p0 = v * Wn[t * 2], p1 = v * Wn[t * 2 + 1];
    #pragma unroll
    for (int off = 32; off; off >>= 1) {
        p0 += __shfl_down(p0, off);
        p1 += __shfl_down(p1, off);
    }
    __shared__ float sm[4];
    if ((t & 63) == 0) { sm[t >> 6] = p0; sm[2 + (t >> 6)] = p1; }
    __syncthreads();
    if (t == 0) {
        out[nd * 2 + 0] = sm[0] + sm[1] + bn[0];
        out[nd * 2 + 1] = sm[2] + sm[3] + bn[1];
    }
}

// ---------------- host launch ----------------
extern "C" void kernel_launch(void* const* d_in, const int* in_sizes, int n_in,
                              void* d_out, int out_size, void* d_ws, size_t ws_size,
                              hipStream_t stream)
{
    const float* x   = (const float*)d_in[0];
    const int*   ei  = (const int*)d_in[1];
    const float* Wq  = (const float*)d_in[2];
    const float* Wk  = (const float*)d_in[3];
    const float* Wv  = (const float*)d_in[4];
    const float* Wo  = (const float*)d_in[5];
    const float* bo  = (const float*)d_in[6];
    const float* W1  = (const float*)d_in[7];
    const float* as1 = (const float*)d_in[8];
    const float* ad1 = (const float*)d_in[9];
    const float* b1  = (const float*)d_in[10];
    const float* g1w = (const float*)d_in[11];
    const float* g1b = (const float*)d_in[12];
    const float* g1m = (const float*)d_in[13];
    const float* W2  = (const float*)d_in[14];
    const float* as2 = (const float*)d_in[15];
    const float* ad2 = (const float*)d_in[16];
    const float* b2  = (const float*)d_in[17];
    const float* g2w = (const float*)d_in[18];
    const float* g2b = (const float*)d_in[19];
    const float* g2m = (const float*)d_in[20];
    const float* Wn  = (const float*)d_in[21];
    const float* bn  = (const float*)d_in[22];
    float* out = (float*)d_out;

    // ---- workspace layout ----
    u16* usw = (u16*)d_ws;
    size_t uo = 0;
    u16* xb  = usw + uo; uo += (size_t)MP * 896;
    u16* h1b = usw + uo; uo += (size_t)MP * 512;
    u16* qb  = usw + uo; uo += (size_t)MP * 128;
    u16* kb  = usw + uo; uo += (size_t)MP * 128;   // later h2b
    u16* vb  = usw + uo; uo += (size_t)MP * 128;
    u16* o1b = usw + uo; uo += (size_t)MP * 512;
    u16* wqT = usw + uo; uo += 128 * 128;
    u16* wkT = usw + uo; uo += 128 * 768;
    u16* wvT = usw + uo; uo += 128 * 768;
    u16* woT = usw + uo; uo += 128 * 256;
    u16* w1T = usw + uo; uo += 512 * 896;
    u16* w2T = usw + uo; uo += 128 * 512;
    float* fws = (float*)(usw + uo);
    size_t fo = 0;
    float* asrc = fws + fo; fo += (size_t)MP * NHEADS;
    float* adst = fws + fo; fo += (size_t)MP * NHEADS;
    float* exf  = fws + fo; fo += (size_t)EEDG * NHEADS;
    float* msum = fws + fo; fo += 512;
    float* vsum = fws + fo; fo += 512;
    int* iws = (int*)(fws + fo);
    size_t io = 0;
    int* rowptr = iws + io; io += NN + 1;
    int* degcur = iws + io; io += 2 * NN;     // [deg | cur]
    int* esrc   = iws + io; io += EEDG;
    int* edst   = iws + io; io += EEDG;
    int* spart  = iws + io; io += 256;
    int* cur    = degcur + NN;
    float* o2  = (float*)xb;   // xb free after h1 GEMM
    u16* h0b = qb;             // reuse q after node_attn
    u16* h2b = kb;             // reuse k after node_attn

    // cast_weights linear work: 770048 weights + 100000 ints + 1024 floats
    const int CW_BLOCKS = (770048 + 2 * NN + 1024 + 255) / 256;

    // --- init: weight casts + zero fills ---
    cast_weights<<<CW_BLOCKS, 256, 0, stream>>>(Wq, Wk, Wv, Wo, W1, W2,
                                                wqT, wkT, wvT, woT, w1T, w2T,
                                                degcur, msum);
    // --- count_deg + x cast (fused, independent work) ---
    prep2<<<EB + 8192, 256, 0, stream>>>(ei, degcur, (const float4*)x, xb);

    // --- CSR scan ---
    scan_bsum<<<SCAN_NB, 256, 0, stream>>>(degcur, spart);
    scan_part<<<1, 256, 0, stream>>>(spart);
    scan_write<<<SCAN_NB, 256, 0, stream>>>(degcur, spart, rowptr);

    // --- Q|K|V GEMM + fill_csr overlapped in one dispatch ---
    gemm_qkv_fill<<<3 * MT + EB, 256, 0, stream>>>(xb, wqT, wkT, wvT, qb, kb, vb,
                                                   ei, rowptr, cur, esrc, edst);
    node_attn_b<<<NN, 128, 0, stream>>>(qb, kb, vb);

    // --- h0 = [x_struct | attn] @ Wo + bo ---
    gemm_mfma<1, 0, 1><<<dim3(1, MT), 256, 0, stream>>>(xb, 896, 128, vb, 128, 128, woT, h0b, 128, bo,
                                                        nullptr, nullptr, nullptr, nullptr);

    // --- h1 = [h0 | x_sem] @ W1 (XCD-swizzled 1D grid) ---
    gemm_w1<<<4 * MT, 256, 0, stream>>>(h0b, xb + 128, w1T, h1b);

    // --- GAT layer 1: dots -> CSR-ordered edge exp -> barrier-free gather ---
    att_dots1_b<<<NN, 256, 0, stream>>>(h1b, as1, ad1, asrc, adst);
    edge_exp<NHEADS><<<EB, 256, 0, stream>>>(esrc, edst, asrc, adst, exf);
    agg1_f<<<NN, 128, 0, stream>>>(rowptr, esrc, exf, h1b, b1, o1b);

    // --- graph norm 1 + ELU (bf16 in place) ---
    colstat_b<<<(NN + 127) / 128, H1D, 0, stream>>>(o1b, msum, vsum, NN, 128);
    apply_norm_elu_b<<<(NN + 127) / 128, H1D, 0, stream>>>(o1b, msum, vsum, g1m, g1w, g1b, NN, 128);

    // --- GAT layer 2: W2 GEMM with fused att-dots ---
    gemm_mfma<1, 1, 1><<<dim3(1, MT), 256, 0, stream>>>(o1b, 512, 512, (const u16*)nullptr, 0, 0, w2T, h2b, 128,
                                                        nullptr, as2, ad2, asrc, adst);
    edge_exp<1><<<EB, 256, 0, stream>>>(esrc, edst, asrc, adst, exf);
    agg2_f<<<(NN + 3) / 4, 256, 0, stream>>>(rowptr, esrc, exf, h2b, b2, o2, msum);

    // --- graph norm 2 + ELU + projection ---
    colstat<<<(NN + 127) / 128, HIDD, 0, stream>>>(o2, msum, vsum, NN, 128);
    norm2_proj<<<NN, 128, 0, stream>>>(o2, msum, vsum, g2m, g2w, g2b, Wn, bn, out);
}

// Round 12
// 585.732 us; speedup vs baseline: 2.1605x; 1.0085x over previous
//
#include <hip/hip_runtime.h>
#include <math.h>

#define NN 50000
#define NE 500000
#define EEDG 550000          // NE + NN self loops
#define SDIM 128             // STRUCT
#define MDIM 768             // SEM
#define HIDD 128             // HID
#define NHEADS 4
#define INDIM 896            // STRUCT + SEM
#define H1D 512              // HEADS*HID
#define SCAN_NB 196          // ceil(NN/256)
#define MP 50048             // NN padded to 128*391
#define MT 391               // row tiles of 128
#define EB 2149              // ceil(EEDG/256)

typedef unsigned short u16;
typedef unsigned int u32;
typedef __attribute__((ext_vector_type(8))) short short8;
typedef __attribute__((ext_vector_type(4))) float f32x4;

// ---------------- bf16 helpers ----------------
__device__ __forceinline__ u16 f2bf(float f) {
    union { float f; u32 u; } v; v.f = f;
    u32 r = v.u + 0x7FFFu + ((v.u >> 16) & 1u);
    return (u16)(r >> 16);
}
__device__ __forceinline__ float bf2f(u16 h) {
    union { u32 u; float f; } v; v.u = ((u32)h) << 16;
    return v.f;
}

__device__ __forceinline__ void gl_lds16(const u16* g, u16* l) {
    __builtin_amdgcn_global_load_lds(
        (const __attribute__((address_space(1))) void*)g,
        (__attribute__((address_space(3))) void*)l, 16, 0, 0);
}

// ---------------- utility ----------------
__device__ __forceinline__ void edge_sd(const int* __restrict__ ei, int e, int& s, int& d) {
    if (e < NE) { s = ei[e]; d = ei[NE + e]; }
    else        { s = e - NE; d = e - NE; }
}

// ---------------- fused init: weight casts (transposed) + zero fills ----------------
__global__ __launch_bounds__(256) void cast_weights(
    const float* __restrict__ Wq, const float* __restrict__ Wk, const float* __restrict__ Wv,
    const float* __restrict__ Wo, const float* __restrict__ W1, const float* __restrict__ W2,
    u16* __restrict__ wqT, u16* __restrict__ wkT, u16* __restrict__ wvT,
    u16* __restrict__ woT, u16* __restrict__ w1T, u16* __restrict__ w2T,
    int* __restrict__ degcur, float* __restrict__ msum)
{
    const int SQ = 128 * 128, SK = 128 * 768, SV = 128 * 768,
              SO = 256 * 128, S1 = 896 * 512, S2 = 512 * 128;
    long i = (long)blockIdx.x * 256 + threadIdx.x;
    long w = i;
    if (w < SQ) { int n = (int)(w / 128), k = (int)(w % 128); wqT[w] = f2bf(Wq[(size_t)k * 128 + n]); return; }
    w -= SQ;
    if (w < SK) { int n = (int)(w / 768), k = (int)(w % 768); wkT[w] = f2bf(Wk[(size_t)k * 128 + n]); return; }
    w -= SK;
    if (w < SV) { int n = (int)(w / 768), k = (int)(w % 768); wvT[w] = f2bf(Wv[(size_t)k * 128 + n]); return; }
    w -= SV;
    if (w < SO) { int n = (int)(w / 256), k = (int)(w % 256); woT[w] = f2bf(Wo[(size_t)k * 128 + n]); return; }
    w -= SO;
    if (w < S1) { int n = (int)(w / 896), k = (int)(w % 896); w1T[w] = f2bf(W1[(size_t)k * 512 + n]); return; }
    w -= S1;
    if (w < S2) { int n = (int)(w / 512), k = (int)(w % 512); w2T[w] = f2bf(W2[(size_t)k * 128 + n]); return; }
    w -= S2;
    if (w < 2 * NN) { degcur[w] = 0; return; }
    w -= 2 * NN;
    if (w < 1024) msum[w] = 0.f;
}

// ---------------- fused: count_deg + x cast/pad (FLAT identity copy) ----------------
__global__ __launch_bounds__(256) void prep2(const int* __restrict__ ei, int* __restrict__ deg,
                                             const float4* __restrict__ x4, short4* __restrict__ xb4)
{
    if (blockIdx.x < EB) {
        int e = blockIdx.x * 256 + threadIdx.x;
        if (e >= EEDG) return;
        int d = e < NE ? ei[NE + e] : e - NE;
        atomicAdd(&deg[d], 1);
        return;
    }
    const long CAST  = (long)NN * 224;   // x and xb are both row-major contiguous: identity map
    const long TOTAL = (long)MP * 224;
    long i = (long)(blockIdx.x - EB) * 256 + threadIdx.x;
    long stride = (long)(gridDim.x - EB) * 256;
    for (; i < TOTAL; i += stride) {
        short4 o = make_short4(0, 0, 0, 0);
        if (i < CAST) {
            float4 v = x4[i];
            o.x = (short)f2bf(v.x); o.y = (short)f2bf(v.y);
            o.z = (short)f2bf(v.z); o.w = (short)f2bf(v.w);
        }
        xb4[i] = o;
    }
}

// ---------------- CSR scan ----------------
__global__ __launch_bounds__(256) void scan_bsum(const int* __restrict__ deg, int* __restrict__ part) {
    __shared__ int s[256];
    int t = threadIdx.x;
    int idx = blockIdx.x * 256 + t;
    s[t] = idx < NN ? deg[idx] : 0;
    __syncthreads();
    for (int off = 128; off; off >>= 1) {
        if (t < off) s[t] += s[t + off];
        __syncthreads();
    }
    if (t == 0) part[blockIdx.x] = s[0];
}

__global__ __launch_bounds__(256) void scan_part(int* __restrict__ part) {
    __shared__ int s[256];
    int t = threadIdx.x;
    int v = t < SCAN_NB ? part[t] : 0;
    s[t] = v;
    __syncthreads();
    for (int off = 1; off < 256; off <<= 1) {
        int x = t >= off ? s[t - off] : 0;
        __syncthreads();
        s[t] += x;
        __syncthreads();
    }
    if (t < SCAN_NB) part[t] = s[t] - v;   // exclusive
}

__global__ __launch_bounds__(256) void scan_write(const int* __restrict__ deg, const int* __restrict__ part,
                                                  int* __restrict__ rowptr) {
    __shared__ int s[256];
    int t = threadIdx.x;
    int idx = blockIdx.x * 256 + t;
    int v = idx < NN ? deg[idx] : 0;
    s[t] = v;
    __syncthreads();
    for (int off = 1; off < 256; off <<= 1) {
        int x = t >= off ? s[t - off] : 0;
        __syncthreads();
        s[t] += x;
        __syncthreads();
    }
    if (idx < NN) rowptr[idx] = part[blockIdx.x] + s[t] - v;
    if (idx == NN - 1) rowptr[NN] = EEDG;
}

// ---------------- CSR-ordered per-edge softmax numerators ----------------
template<int H>
__global__ __launch_bounds__(256) void edge_exp(const int* __restrict__ esrc, const int* __restrict__ edst,
    const float* __restrict__ asrc, const float* __restrict__ adst, float* __restrict__ exf)
{
    int i = blockIdx.x * 256 + threadIdx.x;
    if (i >= EEDG) return;
    int s = esrc[i], d = edst[i];
    if (H == 4) {
        float4 as = *(const float4*)(asrc + s * 4);
        float4 ad = *(const float4*)(adst + d * 4);
        float4 o;
        float a;
        a = as.x + ad.x; a = a >= 0.f ? a : 0.2f * a; o.x = expf(a);
        a = as.y + ad.y; a = a >= 0.f ? a : 0.2f * a; o.y = expf(a);
        a = as.z + ad.z; a = a >= 0.f ? a : 0.2f * a; o.z = expf(a);
        a = as.w + ad.w; a = a >= 0.f ? a : 0.2f * a; o.w = expf(a);
        *(float4*)(exf + (size_t)i * 4) = o;
    } else {
        float a = asrc[s] + adst[d];
        a = a >= 0.f ? a : 0.2f * a;
        exf[i] = expf(a);
    }
}

// ---------------- MFMA bf16 GEMM body (optional fused att-dot epilogue) ----------------
template<int OUT_BF16, int DOTS, int DH>
__device__ __forceinline__ void gemm_body(
    u16* __restrict__ Asm, u16* __restrict__ Bsm,
    const u16* __restrict__ A1, int lda1, int K1,
    const u16* __restrict__ A2, int lda2, int K2,
    const u16* __restrict__ Bw,
    void* __restrict__ Cout, int ldc,
    const float* __restrict__ bias, int row0, int col0,
    const float* __restrict__ dvs, const float* __restrict__ dvd,
    float* __restrict__ aout_s, float* __restrict__ aout_d)
{
    const int tid = threadIdx.x;
    const int wave = tid >> 6, lane = tid & 63;
    const int wr = wave >> 1, wc = wave & 1;
    const int K = K1 + K2;
    const int srow = tid >> 2;
    const int skp = (tid & 3) * 8;
    const int l15 = lane & 15, l4 = lane >> 4;

    f32x4 acc[4][4];
    #pragma unroll
    for (int i = 0; i < 4; ++i)
        #pragma unroll
        for (int j = 0; j < 4; ++j)
            acc[i][j] = (f32x4){0.f, 0.f, 0.f, 0.f};

    for (int k0 = 0; k0 < K; k0 += 32) {
        const u16* Ab; int la; int kk;
        if (k0 < K1) { Ab = A1; la = lda1; kk = k0; }
        else         { Ab = A2; la = lda2; kk = k0 - K1; }
        gl_lds16(Ab + (size_t)(row0 + srow) * la + kk + skp,      Asm + srow * 32 + skp);
        gl_lds16(Ab + (size_t)(row0 + srow + 64) * la + kk + skp, Asm + (srow + 64) * 32 + skp);
        gl_lds16(Bw + (size_t)(col0 + srow) * K + k0 + skp,       Bsm + srow * 32 + skp);
        gl_lds16(Bw + (size_t)(col0 + srow + 64) * K + k0 + skp,  Bsm + (srow + 64) * 32 + skp);
        __syncthreads();
        short8 af[4], bfr[4];
        #pragma unroll
        for (int m = 0; m < 4; ++m)
            af[m] = *(const short8*)(Asm + (wr * 64 + m * 16 + l15) * 32 + l4 * 8);
        #pragma unroll
        for (int n = 0; n < 4; ++n)
            bfr[n] = *(const short8*)(Bsm + (wc * 64 + n * 16 + l15) * 32 + l4 * 8);
        #pragma unroll
        for (int m = 0; m < 4; ++m)
            #pragma unroll
            for (int n = 0; n < 4; ++n)
                acc[m][n] = __builtin_amdgcn_mfma_f32_16x16x32_bf16(af[m], bfr[n], acc[m][n], 0, 0, 0);
        __syncthreads();
    }
    #pragma unroll
    for (int m = 0; m < 4; ++m) {
        int r = row0 + wr * 64 + m * 16 + l4 * 4;
        #pragma unroll
        for (int n = 0; n < 4; ++n) {
            int c = col0 + wc * 64 + n * 16 + l15;
            float bv = bias ? bias[c] : 0.f;
            #pragma unroll
            for (int q = 0; q < 4; ++q) {
                float v = acc[m][n][q] + bv;
                if (OUT_BF16) ((u16*)Cout)[(size_t)(r + q) * ldc + c] = f2bf(v);
                else          ((float*)Cout)[(size_t)(r + q) * ldc + c] = v;
            }
        }
    }
    if (DOTS) {
        const int head = (DH == 1) ? 0 : (col0 >> 7);
        const float* svp = dvs + head * 128;
        const float* dvp = dvd + head * 128;
        float sv[4], dv[4];
        #pragma unroll
        for (int n = 0; n < 4; ++n) {
            int cc = wc * 64 + n * 16 + l15;
            sv[n] = svp[cc];
            dv[n] = dvp[cc];
        }
        __shared__ float red[128][2][2];
        #pragma unroll
        for (int m = 0; m < 4; ++m) {
            #pragma unroll
            for (int q = 0; q < 4; ++q) {
                float ps = 0.f, pd = 0.f;
                #pragma unroll
                for (int n = 0; n < 4; ++n) {
                    ps = fmaf(acc[m][n][q], sv[n], ps);
                    pd = fmaf(acc[m][n][q], dv[n], pd);
                }
                #pragma unroll
                for (int off = 1; off < 16; off <<= 1) {
                    ps += __shfl_xor(ps, off);
                    pd += __shfl_xor(pd, off);
                }
                if (l15 == 0) {
                    int lr = wr * 64 + m * 16 + l4 * 4 + q;
                    red[lr][wc][0] = ps;
                    red[lr][wc][1] = pd;
                }
            }
        }
        __syncthreads();
        if (tid < 128) {
            int r = row0 + tid;
            aout_s[(size_t)r * DH + head] = red[tid][0][0] + red[tid][1][0];
            aout_d[(size_t)r * DH + head] = red[tid][0][1] + red[tid][1][1];
        }
    }
}

template<int OUT_BF16, int DOTS, int DH>
__global__ __launch_bounds__(256) void gemm_mfma(
    const u16* __restrict__ A1, int lda1, int K1,
    const u16* __restrict__ A2, int lda2, int K2,
    const u16* __restrict__ Bw,
    void* __restrict__ Cout, int ldc,
    const float* __restrict__ bias,
    const float* __restrict__ dvs, const float* __restrict__ dvd,
    float* __restrict__ aout_s, float* __restrict__ aout_d)
{
    __shared__ u16 Asm[128 * 32];
    __shared__ u16 Bsm[128 * 32];
    gemm_body<OUT_BF16, DOTS, DH>(Asm, Bsm, A1, lda1, K1, A2, lda2, K2, Bw, Cout, ldc, bias,
                                  blockIdx.y * 128, blockIdx.x * 128, dvs, dvd, aout_s, aout_d);
}

// W1 GEMM: 1D grid, bijective XCD-chunked swizzle, col-tile fastest per XCD span.
__global__ __launch_bounds__(256) void gemm_w1(
    const u16* __restrict__ A1, const u16* __restrict__ A2,
    const u16* __restrict__ Bw, u16* __restrict__ Cout)
{
    __shared__ u16 Asm[128 * 32];
    __shared__ u16 Bsm[128 * 32];
    const int nwg = 4 * MT;            // 1564
    const int q = nwg / 8, r = nwg % 8;
    int orig = blockIdx.x;
    int xcd = orig & 7;
    int lg = (xcd < r ? xcd * (q + 1) : r * (q + 1) + (xcd - r) * q) + (orig >> 3);
    int col0 = (lg & 3) * 128;
    int row0 = (lg >> 2) * 128;
    gemm_body<1, 0, 1>(Asm, Bsm, A1, 128, 128, A2, 896, 768, Bw, Cout, 512, nullptr,
                       row0, col0, nullptr, nullptr, nullptr, nullptr);
}

// fused Q|K|V GEMM + fill_csr (independent work overlapped in one dispatch)
__global__ __launch_bounds__(256) void gemm_qkv_fill(
    const u16* __restrict__ xb,
    const u16* __restrict__ wqT, const u16* __restrict__ wkT, const u16* __restrict__ wvT,
    u16* __restrict__ qb, u16* __restrict__ kb, u16* __restrict__ vb,
    const int* __restrict__ ei, const int* __restrict__ rowptr,
    int* __restrict__ cur, int* __restrict__ esrc, int* __restrict__ edst)
{
    __shared__ u16 Asm[128 * 32];
    __shared__ u16 Bsm[128 * 32];
    int bid = blockIdx.x;
    if (bid >= 3 * MT) {
        int e = (bid - 3 * MT) * 256 + threadIdx.x;
        if (e >= EEDG) return;
        int s, d;
        edge_sd(ei, e, s, d);
        int p = rowptr[d] + atomicAdd(&cur[d], 1);
        esrc[p] = s;
        edst[p] = d;
        return;
    }
    int sel = bid / MT;
    int row = bid - sel * MT;
    const u16* A; const u16* B; int K; u16* C;
    if (sel == 0)      { A = xb;       B = wqT; K = 128; C = qb; }
    else if (sel == 1) { A = xb + 128; B = wkT; K = 768; C = kb; }
    else               { A = xb + 128; B = wvT; K = 768; C = vb; }
    gemm_body<1, 0, 1>(Asm, Bsm, A, 896, K, (const u16*)nullptr, 0, 0, B, C, 128, nullptr,
                       row * 128, 0, nullptr, nullptr, nullptr, nullptr);
}

// ---------------- node cross-attention: wave per node, 4 nodes/block ----------------
__global__ __launch_bounds__(256) void node_attn_b(const u16* __restrict__ Q,
                                                   const u16* __restrict__ K,
                                                   u16* __restrict__ V)
{
    int w = threadIdx.x >> 6, l = threadIdx.x & 63;
    int nd = blockIdx.x * 4 + w;
    if (nd >= NN) return;
    size_t base = (size_t)nd * HIDD + l * 2;
    u32 qp = *(const u32*)(Q + base);
    u32 kp = *(const u32*)(K + base);
    float p = bf2f((u16)qp) * bf2f((u16)kp) + bf2f((u16)(qp >> 16)) * bf2f((u16)(kp >> 16));
    #pragma unroll
    for (int off = 32; off; off >>= 1) p += __shfl_down(p, off);
    float s = __shfl(p, 0);
    float sig = 1.f / (1.f + expf(-s));
    u32 vp = *(const u32*)(V + base);
    u32 o = (u32)f2bf(bf2f((u16)vp) * sig) | ((u32)f2bf(bf2f((u16)(vp >> 16)) * sig) << 16);
    *(u32*)(V + base) = o;
}

// ---------------- GAT layer-1 attention dots (from h1) ----------------
__global__ __launch_bounds__(256) void att_dots1_b(const u16* __restrict__ h1,
    const float* __restrict__ asv, const float* __restrict__ adv,
    float* __restrict__ a_src, float* __restrict__ a_dst)
{
    int nd = blockIdx.x;
    int t = threadIdx.x;
    int w = t >> 6, l = t & 63;
    const u16* hr = h1 + (size_t)nd * H1D + w * HIDD;
    const float* sv = asv + w * HIDD;
    const float* dv = adv + w * HIDD;
    float h0v = bf2f(hr[l]), h1v = bf2f(hr[l + 64]);
    float ps = h0v * sv[l] + h1v * sv[l + 64];
    float pd = h0v * dv[l] + h1v * dv[l + 64];
    #pragma unroll
    for (int off = 32; off; off >>= 1) {
        ps += __shfl_down(ps, off);
        pd += __shfl_down(pd, off);
    }
    if (l == 0) { a_src[nd * NHEADS + w] = ps; a_dst[nd * NHEADS + w] = pd; }
}

// ---------------- fused softmax + gather aggregation (barrier-free, 8-deep MLP) ----------------
// 128 threads x 4 cols (uint2), 8-edge unroll.
#define ACC4(P, AA) { \
    n0 = fmaf(bf2f((u16)(P).x), AA, n0); \
    n1 = fmaf(bf2f((u16)((P).x >> 16)), AA, n1); \
    n2 = fmaf(bf2f((u16)(P).y), AA, n2); \
    n3 = fmaf(bf2f((u16)((P).y >> 16)), AA, n3); }

__global__ __launch_bounds__(128) void agg1_f(const int* __restrict__ rowptr, const int* __restrict__ esrc,
    const float* __restrict__ exf,
    const u16* __restrict__ h1b, const float* __restrict__ bias, u16* __restrict__ o1b)
{
    int d = blockIdx.x;
    int t = threadIdx.x;
    int c0 = t * 4;
    int h = t >> 5;
    int beg = rowptr[d], end = rowptr[d + 1];
    float n0 = 0.f, n1 = 0.f, n2 = 0.f, n3 = 0.f, den = 0.f;
    int i = beg;
    for (; i + 7 < end; i += 8) {
        int s0 = esrc[i], s1 = esrc[i+1], s2 = esrc[i+2], s3 = esrc[i+3];
        int s4 = esrc[i+4], s5 = esrc[i+5], s6 = esrc[i+6], s7 = esrc[i+7];
        float a0 = exf[(size_t)i*4+h],     a1 = exf[(size_t)(i+1)*4+h];
        float a2 = exf[(size_t)(i+2)*4+h], a3 = exf[(size_t)(i+3)*4+h];
        float a4 = exf[(size_t)(i+4)*4+h], a5 = exf[(size_t)(i+5)*4+h];
        float a6 = exf[(size_t)(i+6)*4+h], a7 = exf[(size_t)(i+7)*4+h];
        uint2 p0 = *(const uint2*)(h1b + (size_t)s0 * H1D + c0);
        uint2 p1 = *(const uint2*)(h1b + (size_t)s1 * H1D + c0);
        uint2 p2 = *(const uint2*)(h1b + (size_t)s2 * H1D + c0);
        uint2 p3 = *(const uint2*)(h1b + (size_t)s3 * H1D + c0);
        uint2 p4 = *(const uint2*)(h1b + (size_t)s4 * H1D + c0);
        uint2 p5 = *(const uint2*)(h1b + (size_t)s5 * H1D + c0);
        uint2 p6 = *(const uint2*)(h1b + (size_t)s6 * H1D + c0);
        uint2 p7 = *(const uint2*)(h1b + (size_t)s7 * H1D + c0);
        den += ((a0 + a1) + (a2 + a3)) + ((a4 + a5) + (a6 + a7));
        ACC4(p0, a0) ACC4(p1, a1) ACC4(p2, a2) ACC4(p3, a3)
        ACC4(p4, a4) ACC4(p5, a5) ACC4(p6, a6) ACC4(p7, a7)
    }
    for (; i < end; ++i) {
        int sA = esrc[i];
        float aA = exf[(size_t)i * 4 + h];
        uint2 pA = *(const uint2*)(h1b + (size_t)sA * H1D + c0);
        den += aA;
        ACC4(pA, aA)
    }
    float invd = 1.f / (den + 1e-16f);
    float4 bv = *(const float4*)(bias + c0);
    u32 o0 = (u32)f2bf(n0 * invd + bv.x) | ((u32)f2bf(n1 * invd + bv.y) << 16);
    u32 o1 = (u32)f2bf(n2 * invd + bv.z) | ((u32)f2bf(n3 * invd + bv.w) << 16);
    *(uint2*)(o1b + (size_t)d * H1D + c0) = make_uint2(o0, o1);
}

// layer 2: wave per dst (4/block); block 0 zeroes msum/vsum for norm2.
__global__ __launch_bounds__(256) void agg2_f(const int* __restrict__ rowptr, const int* __restrict__ esrc,
    const float* __restrict__ exf,
    const u16* __restrict__ h2b, const float* __restrict__ bias, float* __restrict__ o2,
    float* __restrict__ msum)
{
    if (blockIdx.x == 0) {
        msum[threadIdx.x] = 0.f;
        msum[threadIdx.x + 256] = 0.f;
        msum[threadIdx.x + 512] = 0.f;
        msum[threadIdx.x + 768] = 0.f;
    }
    int w = threadIdx.x >> 6, l = threadIdx.x & 63;
    int d = blockIdx.x * 4 + w;
    if (d >= NN) return;
    int c0 = l * 2;
    int beg = rowptr[d], end = rowptr[d + 1];
    float n0 = 0.f, n1 = 0.f, den = 0.f;
    int i = beg;
    for (; i + 7 < end; i += 8) {
        int s0 = esrc[i], s1 = esrc[i+1], s2 = esrc[i+2], s3 = esrc[i+3];
        int s4 = esrc[i+4], s5 = esrc[i+5], s6 = esrc[i+6], s7 = esrc[i+7];
        float a0 = exf[i],   a1 = exf[i+1], a2 = exf[i+2], a3 = exf[i+3];
        float a4 = exf[i+4], a5 = exf[i+5], a6 = exf[i+6], a7 = exf[i+7];
        u32 p0 = *(const u32*)(h2b + (size_t)s0 * HIDD + c0);
        u32 p1 = *(const u32*)(h2b + (size_t)s1 * HIDD + c0);
        u32 p2 = *(const u32*)(h2b + (size_t)s2 * HIDD + c0);
        u32 p3 = *(const u32*)(h2b + (size_t)s3 * HIDD + c0);
        u32 p4 = *(const u32*)(h2b + (size_t)s4 * HIDD + c0);
        u32 p5 = *(const u32*)(h2b + (size_t)s5 * HIDD + c0);
        u32 p6 = *(const u32*)(h2b + (size_t)s6 * HIDD + c0);
        u32 p7 = *(const u32*)(h2b + (size_t)s7 * HIDD + c0);
        den += ((a0 + a1) + (a2 + a3)) + ((a4 + a5) + (a6 + a7));
        n0 = fmaf(bf2f((u16)p0), a0, n0); n1 = fmaf(bf2f((u16)(p0 >> 16)), a0, n1);
        n0 = fmaf(bf2f((u16)p1), a1, n0); n1 = fmaf(bf2f((u16)(p1 >> 16)), a1, n1);
        n0 = fmaf(bf2f((u16)p2), a2, n0); n1 = fmaf(bf2f((u16)(p2 >> 16)), a2, n1);
        n0 = fmaf(bf2f((u16)p3), a3, n0); n1 = fmaf(bf2f((u16)(p3 >> 16)), a3, n1);
        n0 = fmaf(bf2f((u16)p4), a4, n0); n1 = fmaf(bf2f((u16)(p4 >> 16)), a4, n1);
        n0 = fmaf(bf2f((u16)p5), a5, n0); n1 = fmaf(bf2f((u16)(p5 >> 16)), a5, n1);
        n0 = fmaf(bf2f((u16)p6), a6, n0); n1 = fmaf(bf2f((u16)(p6 >> 16)), a6, n1);
        n0 = fmaf(bf2f((u16)p7), a7, n0); n1 = fmaf(bf2f((u16)(p7 >> 16)), a7, n1);
    }
    for (; i < end; ++i) {
        int sA = esrc[i];
        float aA = exf[i];
        u32 pA = *(const u32*)(h2b + (size_t)sA * HIDD + c0);
        den += aA;
        n0 = fmaf(bf2f((u16)pA), aA, n0);
        n1 = fmaf(bf2f((u16)(pA >> 16)), aA, n1);
    }
    float invd = 1.f / (den + 1e-16f);
    o2[(size_t)d * HIDD + c0]     = n0 * invd + bias[c0];
    o2[(size_t)d * HIDD + c0 + 1] = n1 * invd + bias[c0 + 1];
}

// ---------------- graph norm ----------------
__global__ void colstat_b(const u16* __restrict__ x, float* __restrict__ msum,
                          float* __restrict__ vsum, int n, int rpb)
{
    int C = blockDim.x;
    int c = threadIdx.x;
    int r0 = blockIdx.x * rpb;
    int r1 = min(n, r0 + rpb);
    float s = 0.f, s2 = 0.f;
    for (int r = r0; r < r1; ++r) {
        float v = bf2f(x[(size_t)r * C + c]);
        s += v;
        s2 += v * v;
    }
    atomicAdd(&msum[c], s);
    atomicAdd(&vsum[c], s2);
}

__global__ void apply_norm_elu_b(u16* __restrict__ x, const float* __restrict__ msum,
                                 const float* __restrict__ vsum, const float* __restrict__ ms,
                                 const float* __restrict__ w, const float* __restrict__ b,
                                 int n, int rpb)
{
    int C = blockDim.x;
    int c = threadIdx.x;
    const float invn = 1.f / (float)NN;
    float mean = msum[c] * invn;
    float sub = mean * ms[c];
    float var = vsum[c] * invn - 2.f * sub * mean + sub * sub;
    float inv = rsqrtf(var + 1e-5f);
    float wc = w[c] * inv, bc = b[c];
    int r0 = blockIdx.x * rpb;
    int r1 = min(n, r0 + rpb);
    for (int r = r0; r < r1; ++r) {
        float v = (bf2f(x[(size_t)r * C + c]) - sub) * wc + bc;
        v = v > 0.f ? v : expm1f(v);
        x[(size_t)r * C + c] = f2bf(v);
    }
}

__global__ void colstat(const float* __restrict__ x, float* __restrict__ msum,
                        float* __restrict__ vsum, int n, int rpb)
{
    int C = blockDim.x;
    int c = threadIdx.x;
    int r0 = blockIdx.x * rpb;
    int r1 = min(n, r0 + rpb);
    float s = 0.f, s2 = 0.f;
    for (int r = r0; r < r1; ++r) {
        float v = x[(size_t)r * C + c];
        s += v;
        s2 += v * v;
    }
    atomicAdd(&msum[c], s);
    atomicAdd(&vsum[c], s2);
}

// ---------------- fused norm2 + ELU + final projection ----------------
__global__ __launch_bounds__(128) void norm2_proj(const float* __restrict__ o2,
    const float* __restrict__ msum, const float* __restrict__ vsum,
    const float* __restrict__ ms, const float* __restrict__ w, const float* __restrict__ b,
    const float* __restrict__ Wn, const float* __restrict__ bn, float* __restrict__ out)
{
    int nd = blockIdx.x;
    int t = threadIdx.x;
    const float invn = 1.f / (float)NN;
    float mean = msum[t] * invn;
    float sub = mean * ms[t];
    float var = vsum[t] * invn - 2.f * sub * mean + sub * sub;
    float inv = rsqrtf(var + 1e-5f);
    float v = (o2[(size_t)nd * HIDD + t] - sub) * w[t] * inv + b[t];
    v = v > 0.f ? v : expm1f(v);
    float p0 = v * Wn[t * 2], p1 = v * Wn[t * 2 + 1];
    #pragma unroll
    for (int off = 32; off; off >>= 1) {
        p0 += __shfl_down(p0, off);
        p1 += __shfl_down(p1, off);
    }
    __shared__ float sm[4];
    if ((t & 63) == 0) { sm[t >> 6] = p0; sm[2 + (t >> 6)] = p1; }
    __syncthreads();
    if (t == 0) {
        out[nd * 2 + 0] = sm[0] + sm[1] + bn[0];
        out[nd * 2 + 1] = sm[2] + sm[3] + bn[1];
    }
}

// ---------------- host launch ----------------
extern "C" void kernel_launch(void* const* d_in, const int* in_sizes, int n_in,
                              void* d_out, int out_size, void* d_ws, size_t ws_size,
                              hipStream_t stream)
{
    const float* x   = (const float*)d_in[0];
    const int*   ei  = (const int*)d_in[1];
    const float* Wq  = (const float*)d_in[2];
    const float* Wk  = (const float*)d_in[3];
    const float* Wv  = (const float*)d_in[4];
    const float* Wo  = (const float*)d_in[5];
    const float* bo  = (const float*)d_in[6];
    const float* W1  = (const float*)d_in[7];
    const float* as1 = (const float*)d_in[8];
    const float* ad1 = (const float*)d_in[9];
    const float* b1  = (const float*)d_in[10];
    const float* g1w = (const float*)d_in[11];
    const float* g1b = (const float*)d_in[12];
    const float* g1m = (const float*)d_in[13];
    const float* W2  = (const float*)d_in[14];
    const float* as2 = (const float*)d_in[15];
    const float* ad2 = (const float*)d_in[16];
    const float* b2  = (const float*)d_in[17];
    const float* g2w = (const float*)d_in[18];
    const float* g2b = (const float*)d_in[19];
    const float* g2m = (const float*)d_in[20];
    const float* Wn  = (const float*)d_in[21];
    const float* bn  = (const float*)d_in[22];
    float* out = (float*)d_out;

    // ---- workspace layout ----
    u16* usw = (u16*)d_ws;
    size_t uo = 0;
    u16* xb  = usw + uo; uo += (size_t)MP * 896;
    u16* h1b = usw + uo; uo += (size_t)MP * 512;
    u16* qb  = usw + uo; uo += (size_t)MP * 128;
    u16* kb  = usw + uo; uo += (size_t)MP * 128;   // later h2b
    u16* vb  = usw + uo; uo += (size_t)MP * 128;
    u16* o1b = usw + uo; uo += (size_t)MP * 512;
    u16* wqT = usw + uo; uo += 128 * 128;
    u16* wkT = usw + uo; uo += 128 * 768;
    u16* wvT = usw + uo; uo += 128 * 768;
    u16* woT = usw + uo; uo += 128 * 256;
    u16* w1T = usw + uo; uo += 512 * 896;
    u16* w2T = usw + uo; uo += 128 * 512;
    float* fws = (float*)(usw + uo);
    size_t fo = 0;
    float* asrc = fws + fo; fo += (size_t)MP * NHEADS;
    float* adst = fws + fo; fo += (size_t)MP * NHEADS;
    float* exf  = fws + fo; fo += (size_t)EEDG * NHEADS;
    float* msum = fws + fo; fo += 512;
    float* vsum = fws + fo; fo += 512;
    int* iws = (int*)(fws + fo);
    size_t io = 0;
    int* rowptr = iws + io; io += NN + 1;
    int* degcur = iws + io; io += 2 * NN;     // [deg | cur]
    int* esrc   = iws + io; io += EEDG;
    int* edst   = iws + io; io += EEDG;
    int* spart  = iws + io; io += 256;
    int* cur    = degcur + NN;
    float* o2  = (float*)xb;   // xb free after h1 GEMM
    u16* h0b = qb;             // reuse q after node_attn
    u16* h2b = kb;             // reuse k after node_attn

    // cast_weights linear work: 770048 weights + 100000 ints + 1024 floats
    const int CW_BLOCKS = (770048 + 2 * NN + 1024 + 255) / 256;

    // --- init: weight casts + zero fills ---
    cast_weights<<<CW_BLOCKS, 256, 0, stream>>>(Wq, Wk, Wv, Wo, W1, W2,
                                                wqT, wkT, wvT, woT, w1T, w2T,
                                                degcur, msum);
    // --- count_deg + x cast (fused; flat identity copy) ---
    prep2<<<EB + 8192, 256, 0, stream>>>(ei, degcur, (const float4*)x, (short4*)xb);

    // --- CSR scan ---
    scan_bsum<<<SCAN_NB, 256, 0, stream>>>(degcur, spart);
    scan_part<<<1, 256, 0, stream>>>(spart);
    scan_write<<<SCAN_NB, 256, 0, stream>>>(degcur, spart, rowptr);

    // --- Q|K|V GEMM + fill_csr overlapped in one dispatch ---
    gemm_qkv_fill<<<3 * MT + EB, 256, 0, stream>>>(xb, wqT, wkT, wvT, qb, kb, vb,
                                                   ei, rowptr, cur, esrc, edst);
    node_attn_b<<<(NN + 3) / 4, 256, 0, stream>>>(qb, kb, vb);

    // --- h0 = [x_struct | attn] @ Wo + bo ---
    gemm_mfma<1, 0, 1><<<dim3(1, MT), 256, 0, stream>>>(xb, 896, 128, vb, 128, 128, woT, h0b, 128, bo,
                                                        nullptr, nullptr, nullptr, nullptr);

    // --- h1 = [h0 | x_sem] @ W1 (XCD-swizzled 1D grid) ---
    gemm_w1<<<4 * MT, 256, 0, stream>>>(h0b, xb + 128, w1T, h1b);

    // --- GAT layer 1: dots -> CSR-ordered edge exp -> barrier-free gather ---
    att_dots1_b<<<NN, 256, 0, stream>>>(h1b, as1, ad1, asrc, adst);
    edge_exp<NHEADS><<<EB, 256, 0, stream>>>(esrc, edst, asrc, adst, exf);
    agg1_f<<<NN, 128, 0, stream>>>(rowptr, esrc, exf, h1b, b1, o1b);

    // --- graph norm 1 + ELU (bf16 in place) ---
    colstat_b<<<(NN + 127) / 128, H1D, 0, stream>>>(o1b, msum, vsum, NN, 128);
    apply_norm_elu_b<<<(NN + 127) / 128, H1D, 0, stream>>>(o1b, msum, vsum, g1m, g1w, g1b, NN, 128);

    // --- GAT layer 2: W2 GEMM with fused att-dots ---
    gemm_mfma<1, 1, 1><<<dim3(1, MT), 256, 0, stream>>>(o1b, 512, 512, (const u16*)nullptr, 0, 0, w2T, h2b, 128,
                                                        nullptr, as2, ad2, asrc, adst);
    edge_exp<1><<<EB, 256, 0, stream>>>(esrc, edst, asrc, adst, exf);
    agg2_f<<<(NN + 3) / 4, 256, 0, stream>>>(rowptr, esrc, exf, h2b, b2, o2, msum);

    // --- graph norm 2 + ELU + projection ---
    colstat<<<(NN + 127) / 128, HIDD, 0, stream>>>(o2, msum, vsum, NN, 128);
    norm2_proj<<<NN, 128, 0, stream>>>(o2, msum, vsum, g2m, g2w, g2b, Wn, bn, out);
}